// Round 1
// baseline (192.110 us; speedup 1.0000x reference)
//
#include <hip/hip_runtime.h>
#include <hip/hip_bf16.h>
#include <stdint.h>

typedef __attribute__((ext_vector_type(8))) short short8;
typedef __attribute__((ext_vector_type(4))) float floatx4;
typedef __attribute__((ext_vector_type(4))) int int4v;

__device__ __forceinline__ unsigned short f2bf(float f) {
    unsigned u = __float_as_uint(f);
    u += 0x7fffu + ((u >> 16) & 1u);   // RNE
    return (unsigned short)(u >> 16);
}

// ---------------- f32 -> bf16 conversion ----------------
__global__ __launch_bounds__(256)
void cvt_kernel(const float* __restrict__ in, unsigned short* __restrict__ out, long n4) {
    long i = (long)blockIdx.x * blockDim.x + threadIdx.x;
    long stride = (long)gridDim.x * blockDim.x;
    for (long idx = i; idx < n4; idx += stride) {
        float4 v = reinterpret_cast<const float4*>(in)[idx];
        uint2 o;
        o.x = (unsigned)f2bf(v.x) | ((unsigned)f2bf(v.y) << 16);
        o.y = (unsigned)f2bf(v.z) | ((unsigned)f2bf(v.w) << 16);
        reinterpret_cast<uint2*>(out)[idx] = o;
    }
}

// ---------------- generic "bt" GEMM: C[m,n] = sum_d A[m,d]*B[n,d] ----------------
// MODE 0: plain (QKV proj).  MODE 1: causal tile skip (scores, skip bx>by).
// MODE 2: causal K-limit (PV: kend = (by+1)*128).
// 128x128 tile, BK=64, 4 waves (2x2), mfma 16x16x32 bf16, XOR-swizzled LDS.
template<typename CT, int MODE>
__global__ __launch_bounds__(256, 2)
void gemm_bt(const unsigned short* __restrict__ A, const unsigned short* __restrict__ B,
             CT* __restrict__ C, int K, int lda, int ldb, int ldc,
             long sA, long sB, long sC)
{
    const int bx = blockIdx.x, by = blockIdx.y, bz = blockIdx.z;
    if (MODE == 1 && bx > by) return;
    A += (long)bz * sA; B += (long)bz * sB; C += (long)bz * sC;
    const int kend = (MODE == 2) ? min(K, (by + 1) * 128) : K;

    __shared__ unsigned short As[128 * 64];
    __shared__ unsigned short Bs[128 * 64];

    const int tid  = threadIdx.x;
    const int lane = tid & 63;
    const int wid  = tid >> 6;
    const int m0 = by * 128, n0 = bx * 128;
    const int wm = (wid >> 1) * 64, wn = (wid & 1) * 64;
    const int frow = lane & 15;          // row/col within 16x16 fragment
    const int fk   = (lane >> 4) * 8;    // k-offset within 32

    floatx4 acc[4][4] = {};

    for (int k0 = 0; k0 < kend; k0 += 64) {
        __syncthreads();
        // stage A and B tiles: 128x64 bf16 each = 1024 chunks of 16B, 256 thr -> 4 rounds
        #pragma unroll
        for (int r = 0; r < 4; ++r) {
            int chunk = r * 256 + tid;
            int row = chunk >> 3;
            int col = (chunk & 7) * 8;
            int swz = (row * 128 + col * 2) ^ ((row & 7) << 4);
            int4v va = *reinterpret_cast<const int4v*>(A + (long)(m0 + row) * lda + k0 + col);
            *reinterpret_cast<int4v*>(reinterpret_cast<char*>(As) + swz) = va;
            int4v vb = *reinterpret_cast<const int4v*>(B + (long)(n0 + row) * ldb + k0 + col);
            *reinterpret_cast<int4v*>(reinterpret_cast<char*>(Bs) + swz) = vb;
        }
        __syncthreads();
        #pragma unroll
        for (int ks = 0; ks < 2; ++ks) {
            short8 af[4], bf[4];
            #pragma unroll
            for (int i = 0; i < 4; ++i) {
                int ar = wm + i * 16 + frow;
                af[i] = *reinterpret_cast<const short8*>(
                    reinterpret_cast<const char*>(As) +
                    ((ar * 128 + (ks * 32 + fk) * 2) ^ ((ar & 7) << 4)));
                int br = wn + i * 16 + frow;
                bf[i] = *reinterpret_cast<const short8*>(
                    reinterpret_cast<const char*>(Bs) +
                    ((br * 128 + (ks * 32 + fk) * 2) ^ ((br & 7) << 4)));
            }
            #pragma unroll
            for (int i = 0; i < 4; ++i)
                #pragma unroll
                for (int j = 0; j < 4; ++j)
                    acc[i][j] = __builtin_amdgcn_mfma_f32_16x16x32_bf16(af[i], bf[j], acc[i][j], 0, 0, 0);
        }
    }

    // epilogue: C/D layout col=lane&15, row=(lane>>4)*4+reg  [m89/m91]
    const int cr0 = m0 + wm + (lane >> 4) * 4;
    const int cc0 = n0 + wn + (lane & 15);
    #pragma unroll
    for (int i = 0; i < 4; ++i)
        #pragma unroll
        for (int j = 0; j < 4; ++j)
            #pragma unroll
            for (int r = 0; r < 4; ++r) {
                long idx = (long)(cr0 + i * 16 + r) * ldc + (cc0 + j * 16);
                float v = acc[i][j][r];
                if constexpr (sizeof(CT) == 4) C[idx] = v;
                else                           C[idx] = (CT)f2bf(v);
            }
}

// ---------------- causal softmax, one block per row; writes bf16 probs in place ----------------
__global__ __launch_bounds__(256)
void softmax_causal(float* __restrict__ Sc) {
    const int q = blockIdx.x;
    const int b = blockIdx.y;
    float* row = Sc + ((long)b * 2048 + q) * 2048;
    const int t = threadIdx.x;
    const int lane = t & 63, wid = t >> 6;

    float vals[8];
    float mx = -INFINITY;
    #pragma unroll
    for (int i = 0; i < 2; ++i) {
        float4 v = *reinterpret_cast<const float4*>(row + i * 1024 + t * 4);
        float tmp[4] = {v.x, v.y, v.z, v.w};
        #pragma unroll
        for (int j = 0; j < 4; ++j) {
            int c = i * 1024 + t * 4 + j;
            float val = (c <= q) ? tmp[j] * 0.03125f : -INFINITY;  // scale 1/sqrt(1024)
            vals[i * 4 + j] = val;
            mx = fmaxf(mx, val);
        }
    }
    #pragma unroll
    for (int o = 32; o > 0; o >>= 1) mx = fmaxf(mx, __shfl_xor(mx, o));
    __shared__ float rmax[4], rsum[4];
    if (lane == 0) rmax[wid] = mx;
    __syncthreads();
    mx = fmaxf(fmaxf(rmax[0], rmax[1]), fmaxf(rmax[2], rmax[3]));

    float s = 0.f;
    #pragma unroll
    for (int k = 0; k < 8; ++k) {
        float e = __expf(vals[k] - mx);
        vals[k] = e;
        s += e;
    }
    #pragma unroll
    for (int o = 32; o > 0; o >>= 1) s += __shfl_xor(s, o);
    if (lane == 0) rsum[wid] = s;
    __syncthreads();
    s = rsum[0] + rsum[1] + rsum[2] + rsum[3];
    const float inv = 1.f / s;

    // in-place bf16 write (all reads happened before the barriers above)
    unsigned short* orow = reinterpret_cast<unsigned short*>(row);
    #pragma unroll
    for (int i = 0; i < 2; ++i) {
        uint2 o;
        o.x = (unsigned)f2bf(vals[i*4+0] * inv) | ((unsigned)f2bf(vals[i*4+1] * inv) << 16);
        o.y = (unsigned)f2bf(vals[i*4+2] * inv) | ((unsigned)f2bf(vals[i*4+3] * inv) << 16);
        *reinterpret_cast<uint2*>(orow + i * 1024 + t * 4) = o;
    }
}

// ---------------- V transpose: Vt[b][v][s] = V[b][s][v] (bf16) ----------------
__global__ __launch_bounds__(256)
void transpose_v(const unsigned short* __restrict__ V, unsigned short* __restrict__ Vt) {
    const int b = blockIdx.z;
    const int v0 = blockIdx.x * 64;
    const int s0 = blockIdx.y * 64;
    __shared__ unsigned short tile[64][68];
    const int t = threadIdx.x;
    const int ii = t >> 4;          // 0..15
    const int jj = (t & 15) * 4;    // 0..60
    #pragma unroll
    for (int p = 0; p < 4; ++p) {
        int s = p * 16 + ii;
        ushort4 val = *reinterpret_cast<const ushort4*>(V + (long)(b * 2048 + s0 + s) * 1024 + v0 + jj);
        *reinterpret_cast<ushort4*>(&tile[s][jj]) = val;
    }
    __syncthreads();
    #pragma unroll
    for (int p = 0; p < 4; ++p) {
        int vl = p * 16 + ii;
        ushort4 o;
        o.x = tile[jj + 0][vl];
        o.y = tile[jj + 1][vl];
        o.z = tile[jj + 2][vl];
        o.w = tile[jj + 3][vl];
        *reinterpret_cast<ushort4*>(Vt + (long)(b * 1024 + v0 + vl) * 2048 + s0 + jj) = o;
    }
}

extern "C" void kernel_launch(void* const* d_in, const int* in_sizes, int n_in,
                              void* d_out, int out_size, void* d_ws, size_t ws_size,
                              hipStream_t stream) {
    const float* x  = (const float*)d_in[0];
    const float* Wq = (const float*)d_in[1];
    const float* Wk = (const float*)d_in[2];
    const float* Wv = (const float*)d_in[3];
    float* out = (float*)d_out;

    // ws layout (bytes):
    //  Xb @ 0      : 16 MiB  bf16 [8192][1024]
    //  Wb @ 16 MiB :  6 MiB  bf16 [3][1024][1024] (q,k,v)
    //  Qb @ 22 MiB : 16 MiB  bf16 [4*2048][1024]
    //  Kb @ 38 MiB : 16 MiB
    //  Vb @ 54 MiB : 16 MiB
    //  Vt @ 70 MiB : 16 MiB  bf16 [4][1024][2048]
    //  Sc @ 86 MiB : 64 MiB  f32  [4][2048][2048] (probs bf16 written in place)
    char* w = (char*)d_ws;
    unsigned short* Xb = (unsigned short*)(w);
    unsigned short* Wb = (unsigned short*)(w + (16ll << 20));
    unsigned short* Qb = (unsigned short*)(w + (22ll << 20));
    unsigned short* Vb = (unsigned short*)(w + (54ll << 20));
    unsigned short* Vt = (unsigned short*)(w + (70ll << 20));
    unsigned short* Kb = (unsigned short*)(w + (38ll << 20));
    float* Sc = (float*)(w + (86ll << 20));

    dim3 blk(256);
    cvt_kernel<<<2048, blk, 0, stream>>>(x,  Xb, (8192ll * 1024) / 4);
    cvt_kernel<<<1024, blk, 0, stream>>>(Wq, Wb,                 (1024ll * 1024) / 4);
    cvt_kernel<<<1024, blk, 0, stream>>>(Wk, Wb + 1024 * 1024,   (1024ll * 1024) / 4);
    cvt_kernel<<<1024, blk, 0, stream>>>(Wv, Wb + 2 * 1024 * 1024, (1024ll * 1024) / 4);

    // QKV projections: z selects {Wq->Qb, Wk->Kb, Wv->Vb}
    gemm_bt<unsigned short, 0><<<dim3(8, 64, 3), blk, 0, stream>>>(
        Xb, Wb, Qb, 1024, 1024, 1024, 1024,
        0, 1024ll * 1024, 8192ll * 1024);

    transpose_v<<<dim3(16, 32, 4), blk, 0, stream>>>(Vb, Vt);

    // scores = Q @ K^T (raw, scale applied in softmax); skip fully-masked tiles
    gemm_bt<float, 1><<<dim3(16, 16, 4), blk, 0, stream>>>(
        Qb, Kb, Sc, 1024, 1024, 1024, 2048,
        2048ll * 1024, 2048ll * 1024, 2048ll * 2048);

    softmax_causal<<<dim3(2048, 4), blk, 0, stream>>>(Sc);

    // out = P @ V   (P bf16 in-place over Sc rows, lda=4096; V^T layout, K-causal)
    gemm_bt<float, 2><<<dim3(8, 16, 4), blk, 0, stream>>>(
        (const unsigned short*)Sc, Vt, out, 2048, 4096, 2048, 1024,
        2048ll * 4096, 1024ll * 2048, 2048ll * 1024);
}

// Round 2
// 180.140 us; speedup vs baseline: 1.0665x; 1.0665x over previous
//
#include <hip/hip_runtime.h>
#include <hip/hip_bf16.h>
#include <stdint.h>

typedef __attribute__((ext_vector_type(8))) short short8;
typedef __attribute__((ext_vector_type(4))) float floatx4;

typedef const __attribute__((address_space(1))) void* gvp;
typedef __attribute__((address_space(3))) void* lvp;

__device__ __forceinline__ unsigned short f2bf(float f) {
    unsigned u = __float_as_uint(f);
    u += 0x7fffu + ((u >> 16) & 1u);   // RNE
    return (unsigned short)(u >> 16);
}

// ---------------- f32 -> bf16 conversion ----------------
__global__ __launch_bounds__(256)
void cvt_kernel(const float* __restrict__ in, unsigned short* __restrict__ out, long n4) {
    long i = (long)blockIdx.x * blockDim.x + threadIdx.x;
    long stride = (long)gridDim.x * blockDim.x;
    for (long idx = i; idx < n4; idx += stride) {
        float4 v = reinterpret_cast<const float4*>(in)[idx];
        uint2 o;
        o.x = (unsigned)f2bf(v.x) | ((unsigned)f2bf(v.y) << 16);
        o.y = (unsigned)f2bf(v.z) | ((unsigned)f2bf(v.w) << 16);
        reinterpret_cast<uint2*>(out)[idx] = o;
    }
}

// ---------------- generic "bt" GEMM: C[m,n] = sum_d A[m,d]*B[n,d] ----------------
// m97 structure: 128x128 tile, BK=64, 4 waves, global_load_lds width-16, linear LDS.
// MODE 0: plain (QKV proj).  MODE 1: causal tile skip (scores, skip bx>by).
// MODE 2: causal K-limit (PV: kend = (by+1)*128).
template<typename CT, int MODE>
__global__ __launch_bounds__(256, 3)
void gemm_bt(const unsigned short* __restrict__ A, const unsigned short* __restrict__ B,
             CT* __restrict__ C, int K, int lda, int ldb, int ldc,
             long sA, long sB, long sC, int nwg)
{
    // ---- XCD-aware bijective remap (T1, m204) ----
    const int gx = gridDim.x, gy = gridDim.y;
    int flat = (blockIdx.z * gy + blockIdx.y) * gx + blockIdx.x;
    {
        int xcd = flat & 7, lid = flat >> 3;
        int q = nwg >> 3, r = nwg & 7;
        flat = (xcd < r ? xcd * (q + 1) : r * (q + 1) + (xcd - r) * q) + lid;
    }
    int bx = flat % gx;
    int t2 = flat / gx;
    int by = t2 % gy;
    const int bz = t2 / gy;
    if (MODE == 1 || MODE == 2) {
        // balance causal work across XCDs: 4-bit reversal of by (gy==16)
        by = ((by & 1) << 3) | ((by & 2) << 1) | ((by & 4) >> 1) | ((by & 8) >> 3);
    }
    if (MODE == 1 && bx > by) return;

    A += (long)bz * sA; B += (long)bz * sB; C += (long)bz * sC;
    const int kend = (MODE == 2) ? min(K, (by + 1) * 128) : K;

    __shared__ unsigned short As[128 * 64];
    __shared__ unsigned short Bs[128 * 64];

    const int tid  = threadIdx.x;
    const int lane = tid & 63;
    const int wid  = tid >> 6;
    const int m0 = by * 128, n0 = bx * 128;
    const int wm = (wid >> 1) * 64, wn = (wid & 1) * 64;
    const int frow = lane & 15;          // row/col within 16x16 fragment
    const int fk   = (lane >> 4) * 8;    // k-offset within 32

    // staging geometry: each 1 KiB chunk = 8 rows x 64 bf16; lane l -> row l>>3, 16B col (l&7)*16
    const int srow = lane >> 3;
    const int scolb = (lane & 7) * 16;

    floatx4 acc[4][4] = {};

    for (int k0 = 0; k0 < kend; k0 += 64) {
        __syncthreads();   // previous tile's compute done before overwrite
        #pragma unroll
        for (int i = 0; i < 4; ++i) {
            const int c = wid * 4 + i;               // chunk 0..15
            const int row = c * 8 + srow;
            const char* ga = reinterpret_cast<const char*>(A + (long)(m0 + row) * lda + k0) + scolb;
            __builtin_amdgcn_global_load_lds((gvp)ga,
                (lvp)(reinterpret_cast<char*>(As) + c * 1024), 16, 0, 0);
            const char* gb = reinterpret_cast<const char*>(B + (long)(n0 + row) * ldb + k0) + scolb;
            __builtin_amdgcn_global_load_lds((gvp)gb,
                (lvp)(reinterpret_cast<char*>(Bs) + c * 1024), 16, 0, 0);
        }
        __syncthreads();   // vmcnt(0) drain: tile staged
        #pragma unroll
        for (int ks = 0; ks < 2; ++ks) {
            short8 af[4], bf[4];
            #pragma unroll
            for (int i = 0; i < 4; ++i) {
                const int ar = wm + i * 16 + frow;
                af[i] = *reinterpret_cast<const short8*>(
                    reinterpret_cast<const char*>(As) + ar * 128 + (ks * 32 + fk) * 2);
                const int br = wn + i * 16 + frow;
                bf[i] = *reinterpret_cast<const short8*>(
                    reinterpret_cast<const char*>(Bs) + br * 128 + (ks * 32 + fk) * 2);
            }
            #pragma unroll
            for (int i = 0; i < 4; ++i)
                #pragma unroll
                for (int j = 0; j < 4; ++j)
                    acc[i][j] = __builtin_amdgcn_mfma_f32_16x16x32_bf16(af[i], bf[j], acc[i][j], 0, 0, 0);
        }
    }

    // epilogue: C/D layout col=lane&15, row=(lane>>4)*4+reg  [m89/m91]
    const int cr0 = m0 + wm + (lane >> 4) * 4;
    const int cc0 = n0 + wn + (lane & 15);
    #pragma unroll
    for (int i = 0; i < 4; ++i)
        #pragma unroll
        for (int j = 0; j < 4; ++j)
            #pragma unroll
            for (int r = 0; r < 4; ++r) {
                long idx = (long)(cr0 + i * 16 + r) * ldc + (cc0 + j * 16);
                float v = acc[i][j][r];
                if constexpr (sizeof(CT) == 4) C[idx] = v;
                else                           C[idx] = (CT)f2bf(v);
            }
}

// ---------------- causal softmax, one block per row; writes bf16 probs in place ----------------
__global__ __launch_bounds__(256)
void softmax_causal(float* __restrict__ Sc) {
    const int q = blockIdx.x;
    const int b = blockIdx.y;
    float* row = Sc + ((long)b * 2048 + q) * 2048;
    const int t = threadIdx.x;
    const int lane = t & 63, wid = t >> 6;

    float vals[8];
    float mx = -INFINITY;
    #pragma unroll
    for (int i = 0; i < 2; ++i) {
        const int c0 = i * 1024 + t * 4;
        if (c0 <= q) {  // skip fully-masked (and never-written) groups
            float4 v = *reinterpret_cast<const float4*>(row + c0);
            float tmp[4] = {v.x, v.y, v.z, v.w};
            #pragma unroll
            for (int j = 0; j < 4; ++j) {
                float val = (c0 + j <= q) ? tmp[j] * 0.03125f : -INFINITY; // 1/sqrt(1024)
                vals[i * 4 + j] = val;
                mx = fmaxf(mx, val);
            }
        } else {
            vals[i*4+0] = vals[i*4+1] = vals[i*4+2] = vals[i*4+3] = -INFINITY;
        }
    }
    #pragma unroll
    for (int o = 32; o > 0; o >>= 1) mx = fmaxf(mx, __shfl_xor(mx, o));
    __shared__ float rmax[4], rsum[4];
    if (lane == 0) rmax[wid] = mx;
    __syncthreads();
    mx = fmaxf(fmaxf(rmax[0], rmax[1]), fmaxf(rmax[2], rmax[3]));

    float s = 0.f;
    #pragma unroll
    for (int k = 0; k < 8; ++k) {
        float e = __expf(vals[k] - mx);
        vals[k] = e;
        s += e;
    }
    #pragma unroll
    for (int o = 32; o > 0; o >>= 1) s += __shfl_xor(s, o);
    if (lane == 0) rsum[wid] = s;
    __syncthreads();
    s = rsum[0] + rsum[1] + rsum[2] + rsum[3];
    const float inv = 1.f / s;

    // in-place bf16 write (all reads happened before the barriers above); masked cols -> 0
    unsigned short* orow = reinterpret_cast<unsigned short*>(row);
    #pragma unroll
    for (int i = 0; i < 2; ++i) {
        uint2 o;
        o.x = (unsigned)f2bf(vals[i*4+0] * inv) | ((unsigned)f2bf(vals[i*4+1] * inv) << 16);
        o.y = (unsigned)f2bf(vals[i*4+2] * inv) | ((unsigned)f2bf(vals[i*4+3] * inv) << 16);
        *reinterpret_cast<uint2*>(orow + i * 1024 + t * 4) = o;
    }
}

// ---------------- V transpose: Vt[b][v][s] = V[b][s][v] (bf16) ----------------
__global__ __launch_bounds__(256)
void transpose_v(const unsigned short* __restrict__ V, unsigned short* __restrict__ Vt) {
    const int b = blockIdx.z;
    const int v0 = blockIdx.x * 64;
    const int s0 = blockIdx.y * 64;
    __shared__ unsigned short tile[64][68];
    const int t = threadIdx.x;
    const int ii = t >> 4;          // 0..15
    const int jj = (t & 15) * 4;    // 0..60
    #pragma unroll
    for (int p = 0; p < 4; ++p) {
        int s = p * 16 + ii;
        ushort4 val = *reinterpret_cast<const ushort4*>(V + (long)(b * 2048 + s0 + s) * 1024 + v0 + jj);
        *reinterpret_cast<ushort4*>(&tile[s][jj]) = val;
    }
    __syncthreads();
    #pragma unroll
    for (int p = 0; p < 4; ++p) {
        int vl = p * 16 + ii;
        ushort4 o;
        o.x = tile[jj + 0][vl];
        o.y = tile[jj + 1][vl];
        o.z = tile[jj + 2][vl];
        o.w = tile[jj + 3][vl];
        *reinterpret_cast<ushort4*>(Vt + (long)(b * 1024 + v0 + vl) * 2048 + s0 + jj) = o;
    }
}

extern "C" void kernel_launch(void* const* d_in, const int* in_sizes, int n_in,
                              void* d_out, int out_size, void* d_ws, size_t ws_size,
                              hipStream_t stream) {
    const float* x  = (const float*)d_in[0];
    const float* Wq = (const float*)d_in[1];
    const float* Wk = (const float*)d_in[2];
    const float* Wv = (const float*)d_in[3];
    float* out = (float*)d_out;

    // ws layout (bytes):
    //  Xb @ 0      : 16 MiB  bf16 [8192][1024]
    //  Wb @ 16 MiB :  6 MiB  bf16 [3][1024][1024] (q,k,v)
    //  Qb @ 22 MiB : 16 MiB  bf16 [4*2048][1024]
    //  Kb @ 38 MiB : 16 MiB
    //  Vb @ 54 MiB : 16 MiB
    //  Vt @ 70 MiB : 16 MiB  bf16 [4][1024][2048]
    //  Sc @ 86 MiB : 64 MiB  f32  [4][2048][2048] (probs bf16 written in place)
    char* w = (char*)d_ws;
    unsigned short* Xb = (unsigned short*)(w);
    unsigned short* Wb = (unsigned short*)(w + (16ll << 20));
    unsigned short* Qb = (unsigned short*)(w + (22ll << 20));
    unsigned short* Kb = (unsigned short*)(w + (38ll << 20));
    unsigned short* Vb = (unsigned short*)(w + (54ll << 20));
    unsigned short* Vt = (unsigned short*)(w + (70ll << 20));
    float* Sc = (float*)(w + (86ll << 20));

    dim3 blk(256);
    cvt_kernel<<<2048, blk, 0, stream>>>(x,  Xb, (8192ll * 1024) / 4);
    cvt_kernel<<<1024, blk, 0, stream>>>(Wq, Wb,                   (1024ll * 1024) / 4);
    cvt_kernel<<<1024, blk, 0, stream>>>(Wk, Wb + 1024 * 1024,     (1024ll * 1024) / 4);
    cvt_kernel<<<1024, blk, 0, stream>>>(Wv, Wb + 2 * 1024 * 1024, (1024ll * 1024) / 4);

    // QKV projections: z selects {Wq->Qb, Wk->Kb, Wv->Vb}
    gemm_bt<unsigned short, 0><<<dim3(8, 64, 3), blk, 0, stream>>>(
        Xb, Wb, Qb, 1024, 1024, 1024, 1024,
        0, 1024ll * 1024, 8192ll * 1024, 8 * 64 * 3);

    transpose_v<<<dim3(16, 32, 4), blk, 0, stream>>>(Vb, Vt);

    // scores = Q @ K^T (raw, scale applied in softmax); skip fully-masked tiles
    gemm_bt<float, 1><<<dim3(16, 16, 4), blk, 0, stream>>>(
        Qb, Kb, Sc, 1024, 1024, 1024, 2048,
        2048ll * 1024, 2048ll * 1024, 2048ll * 2048, 16 * 16 * 4);

    softmax_causal<<<dim3(2048, 4), blk, 0, stream>>>(Sc);

    // out = P @ V   (P bf16 in-place over Sc rows, lda=4096; V^T layout, K-causal)
    gemm_bt<float, 2><<<dim3(8, 16, 4), blk, 0, stream>>>(
        (const unsigned short*)Sc, Vt, out, 2048, 4096, 2048, 1024,
        2048ll * 4096, 1024ll * 2048, 2048ll * 1024, 8 * 16 * 4);
}

// Round 3
// 175.234 us; speedup vs baseline: 1.0963x; 1.0280x over previous
//
#include <hip/hip_runtime.h>
#include <hip/hip_bf16.h>
#include <stdint.h>

typedef __attribute__((ext_vector_type(8))) short short8;
typedef __attribute__((ext_vector_type(4))) float floatx4;

typedef const __attribute__((address_space(1))) void* gvp;
typedef __attribute__((address_space(3))) void* lvp;

__device__ __forceinline__ unsigned short f2bf(float f) {
    unsigned u = __float_as_uint(f);
    u += 0x7fffu + ((u >> 16) & 1u);   // RNE
    return (unsigned short)(u >> 16);
}

#define BAR()   do { asm volatile("" ::: "memory"); __builtin_amdgcn_s_barrier(); asm volatile("" ::: "memory"); } while (0)
#define WAITL() do { asm volatile("s_waitcnt lgkmcnt(0)" ::: "memory"); __builtin_amdgcn_sched_barrier(0); } while (0)
#define WAITV4() asm volatile("s_waitcnt vmcnt(4)" ::: "memory")

// ---------------- f32 -> bf16 conversion ----------------
__global__ __launch_bounds__(256)
void cvt_kernel(const float* __restrict__ in, unsigned short* __restrict__ out, long n4) {
    long i = (long)blockIdx.x * blockDim.x + threadIdx.x;
    long stride = (long)gridDim.x * blockDim.x;
    for (long idx = i; idx < n4; idx += stride) {
        float4 v = reinterpret_cast<const float4*>(in)[idx];
        uint2 o;
        o.x = (unsigned)f2bf(v.x) | ((unsigned)f2bf(v.y) << 16);
        o.y = (unsigned)f2bf(v.z) | ((unsigned)f2bf(v.w) << 16);
        reinterpret_cast<uint2*>(out)[idx] = o;
    }
}

// merged 3-weight conversion (blockIdx.y selects source)
__global__ __launch_bounds__(256)
void cvt_w3(const float* __restrict__ a, const float* __restrict__ b,
            const float* __restrict__ c, unsigned short* __restrict__ out, long n4) {
    const float* in = (blockIdx.y == 0) ? a : (blockIdx.y == 1) ? b : c;
    unsigned short* o = out + (long)blockIdx.y * n4 * 4;
    long i = (long)blockIdx.x * blockDim.x + threadIdx.x;
    long stride = (long)gridDim.x * blockDim.x;
    for (long idx = i; idx < n4; idx += stride) {
        float4 v = reinterpret_cast<const float4*>(in)[idx];
        uint2 ov;
        ov.x = (unsigned)f2bf(v.x) | ((unsigned)f2bf(v.y) << 16);
        ov.y = (unsigned)f2bf(v.z) | ((unsigned)f2bf(v.w) << 16);
        reinterpret_cast<uint2*>(o)[idx] = ov;
    }
}

// ===================== 256x256 8-phase GEMM (T1+T2+T3+T4+T5) =====================
// C[m,n] = sum_d A[m,d]*B[n,d].  BM=BN=256, BK=64, 8 waves (2M x 4N), K multiple of 128.
// LDS: [db][op][half] 8 x 16KB = 128KB. st-swizzle: byte ^= ((row&7)<<4), applied on
// pre-swizzled global source (linear gload_lds dest) and on ds_read address.
// MODE 0: plain. MODE 1: causal tile skip (bx>by).
__device__ __forceinline__ void stage_half(char* slot, const unsigned short* src,
                                           int ld, int k0, int tid) {
    #pragma unroll
    for (int r = 0; r < 2; ++r) {
        const int c = r * 512 + tid;
        const int row = c >> 3;
        const int cs = ((c & 7) * 16) ^ ((row & 7) << 4);
        const char* g = reinterpret_cast<const char*>(src + (long)row * ld + k0) + cs;
        __builtin_amdgcn_global_load_lds((gvp)g,
            (lvp)(slot + r * 8192 + (tid >> 6) * 1024), 16, 0, 0);
    }
}

__device__ __forceinline__ void load_a4(short8 a_[4][2], const char* slot, int mh,
                                        int fr, int csw0, int csw1) {
    #pragma unroll
    for (int i = 0; i < 4; ++i) {
        const int rb = (mh * 64 + i * 16 + fr) * 128;
        a_[i][0] = *reinterpret_cast<const short8*>(slot + rb + csw0);
        a_[i][1] = *reinterpret_cast<const short8*>(slot + rb + csw1);
    }
}

__device__ __forceinline__ void load_b2(short8 b_[2][2], const char* slot, int rbase,
                                        int nh, int fr, int csw0, int csw1) {
    #pragma unroll
    for (int j = 0; j < 2; ++j) {
        const int rb = (rbase + nh * 32 + j * 16 + fr) * 128;
        b_[j][0] = *reinterpret_cast<const short8*>(slot + rb + csw0);
        b_[j][1] = *reinterpret_cast<const short8*>(slot + rb + csw1);
    }
}

__device__ __forceinline__ void mfma16(floatx4 acc[8][4], short8 a_[4][2],
                                       short8 b_[2][2], int mh, int nh) {
    __builtin_amdgcn_s_setprio(1);
    #pragma unroll
    for (int i = 0; i < 4; ++i)
        #pragma unroll
        for (int j = 0; j < 2; ++j) {
            acc[mh*4+i][nh*2+j] = __builtin_amdgcn_mfma_f32_16x16x32_bf16(
                a_[i][0], b_[j][0], acc[mh*4+i][nh*2+j], 0, 0, 0);
            acc[mh*4+i][nh*2+j] = __builtin_amdgcn_mfma_f32_16x16x32_bf16(
                a_[i][1], b_[j][1], acc[mh*4+i][nh*2+j], 0, 0, 0);
        }
    __builtin_amdgcn_s_setprio(0);
}

template<typename CT, int MODE>
__global__ __launch_bounds__(512, 2)
void gemm8p(const unsigned short* __restrict__ A, const unsigned short* __restrict__ B,
            CT* __restrict__ C, int K, int lda, int ldb, int ldc,
            long sA, long sB, long sC, int nwg)
{
    // XCD-aware bijective remap (T1, m204)
    const int gx = gridDim.x, gy = gridDim.y;
    int flat = (blockIdx.z * gy + blockIdx.y) * gx + blockIdx.x;
    {
        int xcd = flat & 7, lid = flat >> 3;
        int q = nwg >> 3, r = nwg & 7;
        flat = (xcd < r ? xcd * (q + 1) : r * (q + 1) + (xcd - r) * q) + lid;
    }
    const int bx = flat % gx;
    const int t2 = flat / gx;
    const int by = t2 % gy;
    const int bz = t2 / gy;
    if (MODE == 1 && bx > by) return;

    A += (long)bz * sA + (long)by * 256 * lda;   // A panel base (m0 folded)
    B += (long)bz * sB + (long)bx * 256 * ldb;   // B panel base (n0 folded)
    C += (long)bz * sC;

    __shared__ __align__(16) char lds[8 * 16384];   // [db][op][half]
    #define SLOT(db, op, half) (lds + ((((db) << 1 | (op)) << 1 | (half)) * 16384))

    const int tid  = threadIdx.x;
    const int lane = tid & 63;
    const int wid  = tid >> 6;
    const int wm = wid >> 2;          // 0..1  (M wave)
    const int wn = wid & 3;           // 0..3  (N wave)
    const int bh = wn >> 1;           // B half this wave reads
    const int brbase = (wn & 1) * 64; // row base inside that half
    const int fr = lane & 15;
    const int csw0 = ((lane >> 4) * 16) ^ ((fr & 7) << 4);        // ks=0
    const int csw1 = (64 + (lane >> 4) * 16) ^ ((fr & 7) << 4);   // ks=1

    const unsigned short* Ah[2] = { A, A + 128ll * lda };
    const unsigned short* Bh[2] = { B, B + 128ll * ldb };

    const int NT = K >> 6;            // K-tiles (>=2, even)
    const int NI = NT >> 1;

    floatx4 acc[8][4] = {};
    short8 a_[4][2];
    short8 b_[2][2][2];               // [nh][j][ks]

    // ---- prologue: t0.{B0,B1,A0,A1}, t1.{B0,B1}; wait tile0 complete ----
    stage_half(SLOT(0,1,0), Bh[0], ldb, 0, tid);
    stage_half(SLOT(0,1,1), Bh[1], ldb, 0, tid);
    stage_half(SLOT(0,0,0), Ah[0], lda, 0, tid);
    stage_half(SLOT(0,0,1), Ah[1], lda, 0, tid);
    stage_half(SLOT(1,1,0), Bh[0], ldb, 64, tid);
    stage_half(SLOT(1,1,1), Bh[1], ldb, 64, tid);
    WAITV4();
    BAR();

    for (int I = 0; I < NI; ++I) {
        const int kA1 = min(2*I + 1, NT - 1) * 64;   // tile t+1 (A halves)
        const int kT2 = min(2*I + 2, NT - 1) * 64;   // tile t+2
        const int kB3 = min(2*I + 3, NT - 1) * 64;   // tile t+3 (B halves)

        // ph1: tile t (db0) quadrant (0,0); stage (t+1).Ah0 -> db1
        load_a4(a_, SLOT(0,0,wm), 0, fr, csw0, csw1);
        load_b2(b_[0], SLOT(0,1,bh), brbase, 0, fr, csw0, csw1);
        stage_half(SLOT(1,0,0), Ah[0], lda, kA1, tid);
        BAR(); WAITL();
        mfma16(acc, a_, b_[0], 0, 0);
        BAR();

        // ph2: quadrant (0,1); stage (t+1).Ah1 -> db1
        load_b2(b_[1], SLOT(0,1,bh), brbase, 1, fr, csw0, csw1);
        stage_half(SLOT(1,0,1), Ah[1], lda, kA1, tid);
        BAR(); WAITL();
        mfma16(acc, a_, b_[1], 0, 1);
        BAR();

        // ph3: quadrant (1,1); stage (t+2).Bh0 -> db0
        load_a4(a_, SLOT(0,0,wm), 1, fr, csw0, csw1);
        stage_half(SLOT(0,1,0), Bh[0], ldb, kT2, tid);
        BAR(); WAITL();
        mfma16(acc, a_, b_[1], 1, 1);
        BAR();

        // ph4: quadrant (1,0); stage (t+2).Bh1 -> db0; counted wait
        stage_half(SLOT(0,1,1), Bh[1], ldb, kT2, tid);
        BAR(); WAITL();
        mfma16(acc, a_, b_[0], 1, 0);
        WAITV4();
        BAR();

        // ph5: tile t+1 (db1) quadrant (0,0); stage (t+2).Ah0 -> db0
        load_a4(a_, SLOT(1,0,wm), 0, fr, csw0, csw1);
        load_b2(b_[0], SLOT(1,1,bh), brbase, 0, fr, csw0, csw1);
        stage_half(SLOT(0,0,0), Ah[0], lda, kT2, tid);
        BAR(); WAITL();
        mfma16(acc, a_, b_[0], 0, 0);
        BAR();

        // ph6: quadrant (0,1); stage (t+2).Ah1 -> db0
        load_b2(b_[1], SLOT(1,1,bh), brbase, 1, fr, csw0, csw1);
        stage_half(SLOT(0,0,1), Ah[1], lda, kT2, tid);
        BAR(); WAITL();
        mfma16(acc, a_, b_[1], 0, 1);
        BAR();

        // ph7: quadrant (1,1); stage (t+3).Bh0 -> db1
        load_a4(a_, SLOT(1,0,wm), 1, fr, csw0, csw1);
        stage_half(SLOT(1,1,0), Bh[0], ldb, kB3, tid);
        BAR(); WAITL();
        mfma16(acc, a_, b_[1], 1, 1);
        BAR();

        // ph8: quadrant (1,0); stage (t+3).Bh1 -> db1; counted wait
        stage_half(SLOT(1,1,1), Bh[1], ldb, kB3, tid);
        BAR(); WAITL();
        mfma16(acc, a_, b_[0], 1, 0);
        WAITV4();
        BAR();
    }

    // epilogue: C/D layout col=lane&15, row=(lane>>4)*4+reg
    const int cr0 = by * 256 + wm * 128 + (lane >> 4) * 4;
    const int cc0 = bx * 256 + wn * 64 + (lane & 15);
    #pragma unroll
    for (int i = 0; i < 8; ++i)
        #pragma unroll
        for (int j = 0; j < 4; ++j)
            #pragma unroll
            for (int r = 0; r < 4; ++r) {
                long idx = (long)(cr0 + i * 16 + r) * ldc + (cc0 + j * 16);
                float v = acc[i][j][r];
                if constexpr (sizeof(CT) == 4) C[idx] = v;
                else                           C[idx] = (CT)f2bf(v);
            }
    #undef SLOT
}

// ===================== 128x128 2-phase GEMM (PV only, MODE2: causal K-limit) =====================
template<typename CT, int MODE>
__global__ __launch_bounds__(256, 3)
void gemm_bt(const unsigned short* __restrict__ A, const unsigned short* __restrict__ B,
             CT* __restrict__ C, int K, int lda, int ldb, int ldc,
             long sA, long sB, long sC, int nwg)
{
    const int gx = gridDim.x, gy = gridDim.y;
    int flat = (blockIdx.z * gy + blockIdx.y) * gx + blockIdx.x;
    {
        int xcd = flat & 7, lid = flat >> 3;
        int q = nwg >> 3, r = nwg & 7;
        flat = (xcd < r ? xcd * (q + 1) : r * (q + 1) + (xcd - r) * q) + lid;
    }
    int bx = flat % gx;
    int t2 = flat / gx;
    int by = t2 % gy;
    const int bz = t2 / gy;
    if (MODE == 2) {
        by = ((by & 1) << 3) | ((by & 2) << 1) | ((by & 4) >> 1) | ((by & 8) >> 3);
    }

    A += (long)bz * sA; B += (long)bz * sB; C += (long)bz * sC;
    const int kend = (MODE == 2) ? min(K, (by + 1) * 128) : K;

    __shared__ unsigned short As[128 * 64];
    __shared__ unsigned short Bs[128 * 64];

    const int tid  = threadIdx.x;
    const int lane = tid & 63;
    const int wid  = tid >> 6;
    const int m0 = by * 128, n0 = bx * 128;
    const int wm = (wid >> 1) * 64, wn = (wid & 1) * 64;
    const int frow = lane & 15;
    const int fk   = (lane >> 4) * 8;

    const int srow = lane >> 3;
    const int scolb = (lane & 7) * 16;

    floatx4 acc[4][4] = {};

    for (int k0 = 0; k0 < kend; k0 += 64) {
        __syncthreads();
        #pragma unroll
        for (int i = 0; i < 4; ++i) {
            const int c = wid * 4 + i;
            const int row = c * 8 + srow;
            const char* ga = reinterpret_cast<const char*>(A + (long)(m0 + row) * lda + k0) + scolb;
            __builtin_amdgcn_global_load_lds((gvp)ga,
                (lvp)(reinterpret_cast<char*>(As) + c * 1024), 16, 0, 0);
            const char* gb = reinterpret_cast<const char*>(B + (long)(n0 + row) * ldb + k0) + scolb;
            __builtin_amdgcn_global_load_lds((gvp)gb,
                (lvp)(reinterpret_cast<char*>(Bs) + c * 1024), 16, 0, 0);
        }
        __syncthreads();
        #pragma unroll
        for (int ks = 0; ks < 2; ++ks) {
            short8 af[4], bf[4];
            #pragma unroll
            for (int i = 0; i < 4; ++i) {
                const int ar = wm + i * 16 + frow;
                af[i] = *reinterpret_cast<const short8*>(
                    reinterpret_cast<const char*>(As) + ar * 128 + (ks * 32 + fk) * 2);
                const int br = wn + i * 16 + frow;
                bf[i] = *reinterpret_cast<const short8*>(
                    reinterpret_cast<const char*>(Bs) + br * 128 + (ks * 32 + fk) * 2);
            }
            #pragma unroll
            for (int i = 0; i < 4; ++i)
                #pragma unroll
                for (int j = 0; j < 4; ++j)
                    acc[i][j] = __builtin_amdgcn_mfma_f32_16x16x32_bf16(af[i], bf[j], acc[i][j], 0, 0, 0);
        }
    }

    const int cr0 = m0 + wm + (lane >> 4) * 4;
    const int cc0 = n0 + wn + (lane & 15);
    #pragma unroll
    for (int i = 0; i < 4; ++i)
        #pragma unroll
        for (int j = 0; j < 4; ++j)
            #pragma unroll
            for (int r = 0; r < 4; ++r) {
                long idx = (long)(cr0 + i * 16 + r) * ldc + (cc0 + j * 16);
                float v = acc[i][j][r];
                if constexpr (sizeof(CT) == 4) C[idx] = v;
                else                           C[idx] = (CT)f2bf(v);
            }
}

// ---------------- causal softmax, one block per row; writes bf16 probs in place ----------------
__global__ __launch_bounds__(256)
void softmax_causal(float* __restrict__ Sc) {
    const int q = blockIdx.x;
    const int b = blockIdx.y;
    float* row = Sc + ((long)b * 2048 + q) * 2048;
    const int t = threadIdx.x;
    const int lane = t & 63, wid = t >> 6;

    float vals[8];
    float mx = -INFINITY;
    #pragma unroll
    for (int i = 0; i < 2; ++i) {
        const int c0 = i * 1024 + t * 4;
        if (c0 <= q) {
            float4 v = *reinterpret_cast<const float4*>(row + c0);
            float tmp[4] = {v.x, v.y, v.z, v.w};
            #pragma unroll
            for (int j = 0; j < 4; ++j) {
                float val = (c0 + j <= q) ? tmp[j] * 0.03125f : -INFINITY;
                vals[i * 4 + j] = val;
                mx = fmaxf(mx, val);
            }
        } else {
            vals[i*4+0] = vals[i*4+1] = vals[i*4+2] = vals[i*4+3] = -INFINITY;
        }
    }
    #pragma unroll
    for (int o = 32; o > 0; o >>= 1) mx = fmaxf(mx, __shfl_xor(mx, o));
    __shared__ float rmax[4], rsum[4];
    if (lane == 0) rmax[wid] = mx;
    __syncthreads();
    mx = fmaxf(fmaxf(rmax[0], rmax[1]), fmaxf(rmax[2], rmax[3]));

    float s = 0.f;
    #pragma unroll
    for (int k = 0; k < 8; ++k) {
        float e = __expf(vals[k] - mx);
        vals[k] = e;
        s += e;
    }
    #pragma unroll
    for (int o = 32; o > 0; o >>= 1) s += __shfl_xor(s, o);
    if (lane == 0) rsum[wid] = s;
    __syncthreads();
    s = rsum[0] + rsum[1] + rsum[2] + rsum[3];
    const float inv = 1.f / s;

    unsigned short* orow = reinterpret_cast<unsigned short*>(row);
    #pragma unroll
    for (int i = 0; i < 2; ++i) {
        uint2 o;
        o.x = (unsigned)f2bf(vals[i*4+0] * inv) | ((unsigned)f2bf(vals[i*4+1] * inv) << 16);
        o.y = (unsigned)f2bf(vals[i*4+2] * inv) | ((unsigned)f2bf(vals[i*4+3] * inv) << 16);
        *reinterpret_cast<uint2*>(orow + i * 1024 + t * 4) = o;
    }
}

// ---------------- V transpose: Vt[b][v][s] = V[b][s][v] (bf16) ----------------
__global__ __launch_bounds__(256)
void transpose_v(const unsigned short* __restrict__ V, unsigned short* __restrict__ Vt) {
    const int b = blockIdx.z;
    const int v0 = blockIdx.x * 64;
    const int s0 = blockIdx.y * 64;
    __shared__ unsigned short tile[64][68];
    const int t = threadIdx.x;
    const int ii = t >> 4;
    const int jj = (t & 15) * 4;
    #pragma unroll
    for (int p = 0; p < 4; ++p) {
        int s = p * 16 + ii;
        ushort4 val = *reinterpret_cast<const ushort4*>(V + (long)(b * 2048 + s0 + s) * 1024 + v0 + jj);
        *reinterpret_cast<ushort4*>(&tile[s][jj]) = val;
    }
    __syncthreads();
    #pragma unroll
    for (int p = 0; p < 4; ++p) {
        int vl = p * 16 + ii;
        ushort4 o;
        o.x = tile[jj + 0][vl];
        o.y = tile[jj + 1][vl];
        o.z = tile[jj + 2][vl];
        o.w = tile[jj + 3][vl];
        *reinterpret_cast<ushort4*>(Vt + (long)(b * 1024 + v0 + vl) * 2048 + s0 + jj) = o;
    }
}

extern "C" void kernel_launch(void* const* d_in, const int* in_sizes, int n_in,
                              void* d_out, int out_size, void* d_ws, size_t ws_size,
                              hipStream_t stream) {
    const float* x  = (const float*)d_in[0];
    const float* Wq = (const float*)d_in[1];
    const float* Wk = (const float*)d_in[2];
    const float* Wv = (const float*)d_in[3];
    float* out = (float*)d_out;

    char* w = (char*)d_ws;
    unsigned short* Xb = (unsigned short*)(w);
    unsigned short* Wb = (unsigned short*)(w + (16ll << 20));
    unsigned short* Qb = (unsigned short*)(w + (22ll << 20));
    unsigned short* Kb = (unsigned short*)(w + (38ll << 20));
    unsigned short* Vb = (unsigned short*)(w + (54ll << 20));
    unsigned short* Vt = (unsigned short*)(w + (70ll << 20));
    float* Sc = (float*)(w + (86ll << 20));

    dim3 blk(256);
    cvt_kernel<<<2048, blk, 0, stream>>>(x, Xb, (8192ll * 1024) / 4);
    cvt_w3<<<dim3(512, 3), blk, 0, stream>>>(Wq, Wk, Wv, Wb, (1024ll * 1024) / 4);

    // QKV projections (8-phase 256^2): z selects {Wq->Qb, Wk->Kb, Wv->Vb}
    gemm8p<unsigned short, 0><<<dim3(4, 32, 3), dim3(512), 0, stream>>>(
        Xb, Wb, Qb, 1024, 1024, 1024, 1024,
        0, 1024ll * 1024, 8192ll * 1024, 4 * 32 * 3);

    transpose_v<<<dim3(16, 32, 4), blk, 0, stream>>>(Vb, Vt);

    // scores = Q @ K^T (8-phase 256^2, causal tile skip)
    gemm8p<float, 1><<<dim3(8, 8, 4), dim3(512), 0, stream>>>(
        Qb, Kb, Sc, 1024, 1024, 1024, 2048,
        2048ll * 1024, 2048ll * 1024, 2048ll * 2048, 8 * 8 * 4);

    softmax_causal<<<dim3(2048, 4), blk, 0, stream>>>(Sc);

    // out = P @ V   (128^2 2-phase, K-causal)
    gemm_bt<float, 2><<<dim3(8, 16, 4), blk, 0, stream>>>(
        (const unsigned short*)Sc, Vt, out, 2048, 4096, 2048, 1024,
        2048ll * 4096, 1024ll * 2048, 2048ll * 1024, 8 * 16 * 4);
}

// Round 4
// 166.917 us; speedup vs baseline: 1.1509x; 1.0498x over previous
//
#include <hip/hip_runtime.h>
#include <hip/hip_bf16.h>
#include <stdint.h>

typedef __attribute__((ext_vector_type(8))) short short8;
typedef __attribute__((ext_vector_type(4))) float floatx4;

typedef const __attribute__((address_space(1))) void* gvp;
typedef __attribute__((address_space(3))) void* lvp;

__device__ __forceinline__ unsigned short f2bf(float f) {
    unsigned u = __float_as_uint(f);
    u += 0x7fffu + ((u >> 16) & 1u);   // RNE
    return (unsigned short)(u >> 16);
}

#define BAR()   do { asm volatile("" ::: "memory"); __builtin_amdgcn_s_barrier(); asm volatile("" ::: "memory"); } while (0)
#define WAITL() do { asm volatile("s_waitcnt lgkmcnt(0)" ::: "memory"); __builtin_amdgcn_sched_barrier(0); } while (0)
#define WAITV4() asm volatile("s_waitcnt vmcnt(4)" ::: "memory")
#define WAITV0() asm volatile("s_waitcnt vmcnt(0)" ::: "memory")

// ---------------- merged f32 -> bf16 conversion: X + Wq + Wk + Wv ----------------
__global__ __launch_bounds__(256)
void cvt_all(const float* __restrict__ x, const float* __restrict__ wq,
             const float* __restrict__ wk, const float* __restrict__ wv,
             unsigned short* __restrict__ Xb, unsigned short* __restrict__ Wb) {
    const long NX = 8192l * 1024 / 4;     // float4 count of X
    const long NW = 1024l * 1024 / 4;     // float4 count per weight (2^18)
    long i = (long)blockIdx.x * blockDim.x + threadIdx.x;
    long stride = (long)gridDim.x * blockDim.x;
    for (long idx = i; idx < NX + 3 * NW; idx += stride) {
        const float* in; unsigned short* out; long off;
        if (idx < NX) { in = x; out = Xb; off = idx; }
        else {
            long r = idx - NX;
            int sel = (int)(r >> 18);
            off = r & (NW - 1);
            in = (sel == 0) ? wq : (sel == 1) ? wk : wv;
            out = Wb + (long)sel * NW * 4;
        }
        float4 v = reinterpret_cast<const float4*>(in)[off];
        uint2 o;
        o.x = (unsigned)f2bf(v.x) | ((unsigned)f2bf(v.y) << 16);
        o.y = (unsigned)f2bf(v.z) | ((unsigned)f2bf(v.w) << 16);
        reinterpret_cast<uint2*>(out)[off] = o;
    }
}

// ===================== 256x256 8-phase GEMM (T1+T2+T3+T4+T5) =====================
// C[m,n] = sum_d A[m,d]*B[n,d].  BM=BN=256, BK=64, 8 waves (2M x 4N), K multiple of 128.
// MODE 0: plain (QKV; bz==2 writes V transposed into Vt). MODE 1: causal tile skip.
__device__ __forceinline__ void stage_half(char* slot, const unsigned short* src,
                                           int ld, int k0, int tid) {
    #pragma unroll
    for (int r = 0; r < 2; ++r) {
        const int c = r * 512 + tid;
        const int row = c >> 3;
        const int cs = ((c & 7) * 16) ^ ((row & 7) << 4);
        const char* g = reinterpret_cast<const char*>(src + (long)row * ld + k0) + cs;
        __builtin_amdgcn_global_load_lds((gvp)g,
            (lvp)(slot + r * 8192 + (tid >> 6) * 1024), 16, 0, 0);
    }
}

__device__ __forceinline__ void load_a4(short8 a_[4][2], const char* slot, int mh,
                                        int fr, int csw0, int csw1) {
    #pragma unroll
    for (int i = 0; i < 4; ++i) {
        const int rb = (mh * 64 + i * 16 + fr) * 128;
        a_[i][0] = *reinterpret_cast<const short8*>(slot + rb + csw0);
        a_[i][1] = *reinterpret_cast<const short8*>(slot + rb + csw1);
    }
}

__device__ __forceinline__ void load_b2(short8 b_[2][2], const char* slot, int rbase,
                                        int nh, int fr, int csw0, int csw1) {
    #pragma unroll
    for (int j = 0; j < 2; ++j) {
        const int rb = (rbase + nh * 32 + j * 16 + fr) * 128;
        b_[j][0] = *reinterpret_cast<const short8*>(slot + rb + csw0);
        b_[j][1] = *reinterpret_cast<const short8*>(slot + rb + csw1);
    }
}

__device__ __forceinline__ void mfma16(floatx4 acc[8][4], short8 a_[4][2],
                                       short8 b_[2][2], int mh, int nh) {
    __builtin_amdgcn_s_setprio(1);
    #pragma unroll
    for (int i = 0; i < 4; ++i)
        #pragma unroll
        for (int j = 0; j < 2; ++j) {
            acc[mh*4+i][nh*2+j] = __builtin_amdgcn_mfma_f32_16x16x32_bf16(
                a_[i][0], b_[j][0], acc[mh*4+i][nh*2+j], 0, 0, 0);
            acc[mh*4+i][nh*2+j] = __builtin_amdgcn_mfma_f32_16x16x32_bf16(
                a_[i][1], b_[j][1], acc[mh*4+i][nh*2+j], 0, 0, 0);
        }
    __builtin_amdgcn_s_setprio(0);
}

template<typename CT, int MODE>
__global__ __launch_bounds__(512, 2)
void gemm8p(const unsigned short* __restrict__ A, const unsigned short* __restrict__ B,
            CT* __restrict__ C, unsigned short* __restrict__ Vt,
            int K, int lda, int ldb, int ldc,
            long sA, long sB, long sC, int nwg)
{
    // XCD-aware bijective remap (T1, m204)
    const int gx = gridDim.x, gy = gridDim.y;
    int flat = (blockIdx.z * gy + blockIdx.y) * gx + blockIdx.x;
    {
        int xcd = flat & 7, lid = flat >> 3;
        int q = nwg >> 3, r = nwg & 7;
        flat = (xcd < r ? xcd * (q + 1) : r * (q + 1) + (xcd - r) * q) + lid;
    }
    const int bx = flat % gx;
    const int t2 = flat / gx;
    const int by = t2 % gy;
    const int bz = t2 / gy;
    if (MODE == 1 && bx > by) return;

    A += (long)bz * sA + (long)by * 256 * lda;   // A panel base (m0 folded)
    B += (long)bz * sB + (long)bx * 256 * ldb;   // B panel base (n0 folded)
    C += (long)bz * sC;

    __shared__ __align__(16) char lds[8 * 16384];   // [db][op][half]
    #define SLOT(db, op, half) (lds + ((((db) << 1 | (op)) << 1 | (half)) * 16384))

    const int tid  = threadIdx.x;
    const int lane = tid & 63;
    const int wid  = tid >> 6;
    const int wm = wid >> 2;          // 0..1  (M wave)
    const int wn = wid & 3;           // 0..3  (N wave)
    const int bh = wn >> 1;           // B half this wave reads
    const int brbase = (wn & 1) * 64; // row base inside that half
    const int fr = lane & 15;
    const int csw0 = ((lane >> 4) * 16) ^ ((fr & 7) << 4);        // ks=0
    const int csw1 = (64 + (lane >> 4) * 16) ^ ((fr & 7) << 4);   // ks=1

    const unsigned short* Ah[2] = { A, A + 128ll * lda };
    const unsigned short* Bh[2] = { B, B + 128ll * ldb };

    const int NT = K >> 6;            // K-tiles (>=2, even)
    const int NI = NT >> 1;

    floatx4 acc[8][4] = {};
    short8 a_[4][2];
    short8 b_[2][2][2];               // [nh][j][ks]

    // ---- prologue: t0.{B0,B1,A0,A1}, t1.{B0,B1}; wait tile0 complete ----
    stage_half(SLOT(0,1,0), Bh[0], ldb, 0, tid);
    stage_half(SLOT(0,1,1), Bh[1], ldb, 0, tid);
    stage_half(SLOT(0,0,0), Ah[0], lda, 0, tid);
    stage_half(SLOT(0,0,1), Ah[1], lda, 0, tid);
    stage_half(SLOT(1,1,0), Bh[0], ldb, 64, tid);
    stage_half(SLOT(1,1,1), Bh[1], ldb, 64, tid);
    WAITV4();
    BAR();

    for (int I = 0; I < NI; ++I) {
        const int kA1 = min(2*I + 1, NT - 1) * 64;
        const int kT2 = min(2*I + 2, NT - 1) * 64;
        const int kB3 = min(2*I + 3, NT - 1) * 64;

        // ph1: tile t (db0) quadrant (0,0); stage (t+1).Ah0 -> db1
        load_a4(a_, SLOT(0,0,wm), 0, fr, csw0, csw1);
        load_b2(b_[0], SLOT(0,1,bh), brbase, 0, fr, csw0, csw1);
        stage_half(SLOT(1,0,0), Ah[0], lda, kA1, tid);
        BAR(); WAITL();
        mfma16(acc, a_, b_[0], 0, 0);
        BAR();

        // ph2: quadrant (0,1); stage (t+1).Ah1 -> db1
        load_b2(b_[1], SLOT(0,1,bh), brbase, 1, fr, csw0, csw1);
        stage_half(SLOT(1,0,1), Ah[1], lda, kA1, tid);
        BAR(); WAITL();
        mfma16(acc, a_, b_[1], 0, 1);
        BAR();

        // ph3: quadrant (1,1); stage (t+2).Bh0 -> db0
        load_a4(a_, SLOT(0,0,wm), 1, fr, csw0, csw1);
        stage_half(SLOT(0,1,0), Bh[0], ldb, kT2, tid);
        BAR(); WAITL();
        mfma16(acc, a_, b_[1], 1, 1);
        BAR();

        // ph4: quadrant (1,0); stage (t+2).Bh1 -> db0; counted wait
        stage_half(SLOT(0,1,1), Bh[1], ldb, kT2, tid);
        BAR(); WAITL();
        mfma16(acc, a_, b_[0], 1, 0);
        WAITV4();
        BAR();

        // ph5: tile t+1 (db1) quadrant (0,0); stage (t+2).Ah0 -> db0
        load_a4(a_, SLOT(1,0,wm), 0, fr, csw0, csw1);
        load_b2(b_[0], SLOT(1,1,bh), brbase, 0, fr, csw0, csw1);
        stage_half(SLOT(0,0,0), Ah[0], lda, kT2, tid);
        BAR(); WAITL();
        mfma16(acc, a_, b_[0], 0, 0);
        BAR();

        // ph6: quadrant (0,1); stage (t+2).Ah1 -> db0
        load_b2(b_[1], SLOT(1,1,bh), brbase, 1, fr, csw0, csw1);
        stage_half(SLOT(0,0,1), Ah[1], lda, kT2, tid);
        BAR(); WAITL();
        mfma16(acc, a_, b_[1], 0, 1);
        BAR();

        // ph7: quadrant (1,1); stage (t+3).Bh0 -> db1
        load_a4(a_, SLOT(1,0,wm), 1, fr, csw0, csw1);
        stage_half(SLOT(1,1,0), Bh[0], ldb, kB3, tid);
        BAR(); WAITL();
        mfma16(acc, a_, b_[1], 1, 1);
        BAR();

        // ph8: quadrant (1,0); stage (t+3).Bh1 -> db1; counted wait
        stage_half(SLOT(1,1,1), Bh[1], ldb, kB3, tid);
        BAR(); WAITL();
        mfma16(acc, a_, b_[0], 1, 0);
        WAITV4();
        BAR();
    }

    if (MODE == 0 && bz == 2) {
        // ---- V path: write C transposed into Vt[b][v][s] via LDS (coalesced) ----
        // Drain stray prefetch gload_lds (clamped t+3 loads) before reusing LDS.
        WAITV0();
        BAR();
        char* T = lds;   // 256(n) x 256(m) bf16 = 128 KiB, 16B-chunk XOR swizzle on m
        #pragma unroll
        for (int i = 0; i < 8; ++i)
            #pragma unroll
            for (int j = 0; j < 4; ++j) {
                const int n = wn * 64 + j * 16 + fr;
                const int m = wm * 128 + ((lane >> 4) << 2) + i * 16;
                uint2 pk;
                pk.x = (unsigned)f2bf(acc[i][j][0]) | ((unsigned)f2bf(acc[i][j][1]) << 16);
                pk.y = (unsigned)f2bf(acc[i][j][2]) | ((unsigned)f2bf(acc[i][j][3]) << 16);
                *reinterpret_cast<uint2*>(T + n * 512 + ((m * 2) ^ ((n & 7) << 4))) = pk;
            }
        __syncthreads();
        const int b  = by >> 3;             // batch (2048 rows each)
        const int s0 = (by & 7) * 256;      // seq offset within batch
        #pragma unroll
        for (int c = 0; c < 16; ++c) {
            const int idx = c * 512 + tid;
            const int n = idx >> 5, k = idx & 31;
            uint4 v = *reinterpret_cast<const uint4*>(T + n * 512 + ((k * 16) ^ ((n & 7) << 4)));
            *reinterpret_cast<uint4*>(Vt + (long)b * (1024 * 2048)
                + (long)(bx * 256 + n) * 2048 + s0 + k * 8) = v;
        }
        return;
    }

    // epilogue: C/D layout col=lane&15, row=(lane>>4)*4+reg
    const int cr0 = by * 256 + wm * 128 + (lane >> 4) * 4;
    const int cc0 = bx * 256 + wn * 64 + (lane & 15);
    #pragma unroll
    for (int i = 0; i < 8; ++i)
        #pragma unroll
        for (int j = 0; j < 4; ++j)
            #pragma unroll
            for (int r = 0; r < 4; ++r) {
                long idx = (long)(cr0 + i * 16 + r) * ldc + (cc0 + j * 16);
                float v = acc[i][j][r];
                if constexpr (sizeof(CT) == 4) C[idx] = v;
                else                           C[idx] = (CT)f2bf(v);
            }
    #undef SLOT
}

// ===================== 128x128 2-phase GEMM (PV only, MODE2: causal K-limit) =====================
template<typename CT, int MODE>
__global__ __launch_bounds__(256, 3)
void gemm_bt(const unsigned short* __restrict__ A, const unsigned short* __restrict__ B,
             CT* __restrict__ C, int K, int lda, int ldb, int ldc,
             long sA, long sB, long sC, int nwg)
{
    const int gx = gridDim.x, gy = gridDim.y;
    int flat = (blockIdx.z * gy + blockIdx.y) * gx + blockIdx.x;
    {
        int xcd = flat & 7, lid = flat >> 3;
        int q = nwg >> 3, r = nwg & 7;
        flat = (xcd < r ? xcd * (q + 1) : r * (q + 1) + (xcd - r) * q) + lid;
    }
    int bx = flat % gx;
    int t2 = flat / gx;
    int by = t2 % gy;
    const int bz = t2 / gy;
    if (MODE == 2) {
        by = ((by & 1) << 3) | ((by & 2) << 1) | ((by & 4) >> 1) | ((by & 8) >> 3);
    }

    A += (long)bz * sA; B += (long)bz * sB; C += (long)bz * sC;
    const int kend = (MODE == 2) ? min(K, (by + 1) * 128) : K;

    __shared__ unsigned short As[128 * 64];
    __shared__ unsigned short Bs[128 * 64];

    const int tid  = threadIdx.x;
    const int lane = tid & 63;
    const int wid  = tid >> 6;
    const int m0 = by * 128, n0 = bx * 128;
    const int wm = (wid >> 1) * 64, wn = (wid & 1) * 64;
    const int frow = lane & 15;
    const int fk   = (lane >> 4) * 8;

    const int srow = lane >> 3;
    const int scolb = (lane & 7) * 16;

    floatx4 acc[4][4] = {};

    for (int k0 = 0; k0 < kend; k0 += 64) {
        __syncthreads();
        #pragma unroll
        for (int i = 0; i < 4; ++i) {
            const int c = wid * 4 + i;
            const int row = c * 8 + srow;
            const char* ga = reinterpret_cast<const char*>(A + (long)(m0 + row) * lda + k0) + scolb;
            __builtin_amdgcn_global_load_lds((gvp)ga,
                (lvp)(reinterpret_cast<char*>(As) + c * 1024), 16, 0, 0);
            const char* gb = reinterpret_cast<const char*>(B + (long)(n0 + row) * ldb + k0) + scolb;
            __builtin_amdgcn_global_load_lds((gvp)gb,
                (lvp)(reinterpret_cast<char*>(Bs) + c * 1024), 16, 0, 0);
        }
        __syncthreads();
        #pragma unroll
        for (int ks = 0; ks < 2; ++ks) {
            short8 af[4], bf[4];
            #pragma unroll
            for (int i = 0; i < 4; ++i) {
                const int ar = wm + i * 16 + frow;
                af[i] = *reinterpret_cast<const short8*>(
                    reinterpret_cast<const char*>(As) + ar * 128 + (ks * 32 + fk) * 2);
                const int br = wn + i * 16 + frow;
                bf[i] = *reinterpret_cast<const short8*>(
                    reinterpret_cast<const char*>(Bs) + br * 128 + (ks * 32 + fk) * 2);
            }
            #pragma unroll
            for (int i = 0; i < 4; ++i)
                #pragma unroll
                for (int j = 0; j < 4; ++j)
                    acc[i][j] = __builtin_amdgcn_mfma_f32_16x16x32_bf16(af[i], bf[j], acc[i][j], 0, 0, 0);
        }
    }

    const int cr0 = m0 + wm + (lane >> 4) * 4;
    const int cc0 = n0 + wn + (lane & 15);
    #pragma unroll
    for (int i = 0; i < 4; ++i)
        #pragma unroll
        for (int j = 0; j < 4; ++j)
            #pragma unroll
            for (int r = 0; r < 4; ++r) {
                long idx = (long)(cr0 + i * 16 + r) * ldc + (cc0 + j * 16);
                float v = acc[i][j][r];
                if constexpr (sizeof(CT) == 4) C[idx] = v;
                else                           C[idx] = (CT)f2bf(v);
            }
}

// ---------------- causal softmax, one block per row; writes bf16 probs in place ----------------
__global__ __launch_bounds__(256)
void softmax_causal(float* __restrict__ Sc) {
    const int q = blockIdx.x;
    const int b = blockIdx.y;
    float* row = Sc + ((long)b * 2048 + q) * 2048;
    const int t = threadIdx.x;
    const int lane = t & 63, wid = t >> 6;
    const int kend = (q | 127) + 1;       // PV reads exactly cols < kend

    float vals[8];
    float mx = -INFINITY;
    #pragma unroll
    for (int i = 0; i < 2; ++i) {
        const int c0 = i * 1024 + t * 4;
        if (c0 <= q) {
            float4 v = *reinterpret_cast<const float4*>(row + c0);
            float tmp[4] = {v.x, v.y, v.z, v.w};
            #pragma unroll
            for (int j = 0; j < 4; ++j) {
                float val = (c0 + j <= q) ? tmp[j] * 0.03125f : -INFINITY;
                vals[i * 4 + j] = val;
                mx = fmaxf(mx, val);
            }
        } else {
            vals[i*4+0] = vals[i*4+1] = vals[i*4+2] = vals[i*4+3] = -INFINITY;
        }
    }
    #pragma unroll
    for (int o = 32; o > 0; o >>= 1) mx = fmaxf(mx, __shfl_xor(mx, o));
    __shared__ float rmax[4], rsum[4];
    if (lane == 0) rmax[wid] = mx;
    __syncthreads();
    mx = fmaxf(fmaxf(rmax[0], rmax[1]), fmaxf(rmax[2], rmax[3]));

    float s = 0.f;
    #pragma unroll
    for (int k = 0; k < 8; ++k) {
        float e = __expf(vals[k] - mx);
        vals[k] = e;
        s += e;
    }
    #pragma unroll
    for (int o = 32; o > 0; o >>= 1) s += __shfl_xor(s, o);
    if (lane == 0) rsum[wid] = s;
    __syncthreads();
    s = rsum[0] + rsum[1] + rsum[2] + rsum[3];
    const float inv = 1.f / s;

    unsigned short* orow = reinterpret_cast<unsigned short*>(row);
    #pragma unroll
    for (int i = 0; i < 2; ++i) {
        const int c0 = i * 1024 + t * 4;
        if (c0 < kend) {
            uint2 o;
            o.x = (unsigned)f2bf(vals[i*4+0] * inv) | ((unsigned)f2bf(vals[i*4+1] * inv) << 16);
            o.y = (unsigned)f2bf(vals[i*4+2] * inv) | ((unsigned)f2bf(vals[i*4+3] * inv) << 16);
            *reinterpret_cast<uint2*>(orow + c0) = o;
        }
    }
}

extern "C" void kernel_launch(void* const* d_in, const int* in_sizes, int n_in,
                              void* d_out, int out_size, void* d_ws, size_t ws_size,
                              hipStream_t stream) {
    const float* x  = (const float*)d_in[0];
    const float* Wq = (const float*)d_in[1];
    const float* Wk = (const float*)d_in[2];
    const float* Wv = (const float*)d_in[3];
    float* out = (float*)d_out;

    char* w = (char*)d_ws;
    unsigned short* Xb = (unsigned short*)(w);
    unsigned short* Wb = (unsigned short*)(w + (16ll << 20));
    unsigned short* Qb = (unsigned short*)(w + (22ll << 20));
    unsigned short* Kb = (unsigned short*)(w + (38ll << 20));
    unsigned short* Vt = (unsigned short*)(w + (70ll << 20));
    float* Sc = (float*)(w + (86ll << 20));

    dim3 blk(256);
    cvt_all<<<2816, blk, 0, stream>>>(x, Wq, Wk, Wv, Xb, Wb);

    // QKV projections (8-phase 256^2): z in {Wq->Qb, Wk->Kb, Wv->Vt (transposed)}
    gemm8p<unsigned short, 0><<<dim3(4, 32, 3), dim3(512), 0, stream>>>(
        Xb, Wb, Qb, Vt, 1024, 1024, 1024, 1024,
        0, 1024ll * 1024, 8192ll * 1024, 4 * 32 * 3);

    // scores = Q @ K^T (8-phase 256^2, causal tile skip)
    gemm8p<float, 1><<<dim3(8, 8, 4), dim3(512), 0, stream>>>(
        Qb, Kb, Sc, nullptr, 1024, 1024, 1024, 2048,
        2048ll * 1024, 2048ll * 1024, 2048ll * 2048, 8 * 8 * 4);

    softmax_causal<<<dim3(2048, 4), blk, 0, stream>>>(Sc);

    // out = P @ V   (128^2 2-phase, K-causal)
    gemm_bt<float, 2><<<dim3(8, 16, 4), blk, 0, stream>>>(
        (const unsigned short*)Sc, Vt, out, 2048, 4096, 2048, 1024,
        2048ll * 4096, 1024ll * 2048, 2048ll * 1024, 8 * 16 * 4);
}

// Round 5
// 161.451 us; speedup vs baseline: 1.1899x; 1.0339x over previous
//
#include <hip/hip_runtime.h>
#include <hip/hip_bf16.h>
#include <stdint.h>

typedef __attribute__((ext_vector_type(8))) short short8;
typedef __attribute__((ext_vector_type(4))) float floatx4;

typedef const __attribute__((address_space(1))) void* gvp;
typedef __attribute__((address_space(3))) void* lvp;

__device__ __forceinline__ unsigned short f2bf(float f) {
    unsigned u = __float_as_uint(f);
    u += 0x7fffu + ((u >> 16) & 1u);   // RNE
    return (unsigned short)(u >> 16);
}

#define BAR()   do { asm volatile("" ::: "memory"); __builtin_amdgcn_s_barrier(); asm volatile("" ::: "memory"); } while (0)
#define WAITL() do { asm volatile("s_waitcnt lgkmcnt(0)" ::: "memory"); __builtin_amdgcn_sched_barrier(0); } while (0)
#define WAITV4() asm volatile("s_waitcnt vmcnt(4)" ::: "memory")
#define WAITV0() asm volatile("s_waitcnt vmcnt(0)" ::: "memory")

// ---------------- conversion: X, Wv straight; Wq, Wk transposed (for G = Wk^T Wq) ----------------
__global__ __launch_bounds__(256)
void cvt_all(const float* __restrict__ x, const float* __restrict__ wq,
             const float* __restrict__ wk, const float* __restrict__ wv,
             unsigned short* __restrict__ Xb, unsigned short* __restrict__ WqT,
             unsigned short* __restrict__ WkT, unsigned short* __restrict__ Wvb) {
    const int b = blockIdx.x, t = threadIdx.x;
    if (b < 2304) {
        const float* in; unsigned short* out; long base;
        if (b < 2048) { in = x;  out = Xb;  base = (long)b * 1024; }
        else          { in = wv; out = Wvb; base = (long)(b - 2048) * 1024; }
        #pragma unroll
        for (int k = 0; k < 4; ++k) {
            long idx = base + k * 256 + t;
            float4 v = reinterpret_cast<const float4*>(in)[idx];
            uint2 o;
            o.x = (unsigned)f2bf(v.x) | ((unsigned)f2bf(v.y) << 16);
            o.y = (unsigned)f2bf(v.z) | ((unsigned)f2bf(v.w) << 16);
            reinterpret_cast<uint2*>(out)[idx] = o;
        }
    } else {
        // 64x64 transpose tiles: out[d][e] = in[e][d], bf16
        const int bb = b - 2304;
        const float* in = (bb < 256) ? wq : wk;
        unsigned short* out = (bb < 256) ? WqT : WkT;
        const int tile = bb & 255;
        const int e0 = (tile >> 4) * 64, d0 = (tile & 15) * 64;
        __shared__ unsigned short ldsT[64][68];
        const int r = t >> 4, cq = t & 15;
        #pragma unroll
        for (int p = 0; p < 4; ++p) {
            const int e = p * 16 + r;
            float4 v = *reinterpret_cast<const float4*>(in + (long)(e0 + e) * 1024 + d0 + cq * 4);
            ldsT[cq*4+0][e] = f2bf(v.x);
            ldsT[cq*4+1][e] = f2bf(v.y);
            ldsT[cq*4+2][e] = f2bf(v.z);
            ldsT[cq*4+3][e] = f2bf(v.w);
        }
        __syncthreads();
        #pragma unroll
        for (int p = 0; p < 4; ++p) {
            const int d = p * 16 + r;
            ushort4 o = *reinterpret_cast<const ushort4*>(&ldsT[d][cq * 4]);
            *reinterpret_cast<ushort4*>(out + (long)(d0 + d) * 1024 + e0 + cq * 4) = o;
        }
    }
}

// ===================== 256x256 8-phase GEMM (T1+T2+T3+T4+T5) =====================
// C[m,n] = sum_d A[m,d]*B[n,d].  BM=BN=256, BK=64, 8 waves (2M x 4N), K multiple of 128.
// MODE 1: causal tile skip (scores). MODE 3: dual job — flat<128: Y=X*B0 plain write;
// flat>=128: V=X*B1 written transposed into Vt.
__device__ __forceinline__ void stage_half(char* slot, const unsigned short* src,
                                           int ld, int k0, int tid) {
    #pragma unroll
    for (int r = 0; r < 2; ++r) {
        const int c = r * 512 + tid;
        const int row = c >> 3;
        const int cs = ((c & 7) * 16) ^ ((row & 7) << 4);
        const char* g = reinterpret_cast<const char*>(src + (long)row * ld + k0) + cs;
        __builtin_amdgcn_global_load_lds((gvp)g,
            (lvp)(slot + r * 8192 + (tid >> 6) * 1024), 16, 0, 0);
    }
}

__device__ __forceinline__ void load_a4(short8 a_[4][2], const char* slot, int mh,
                                        int fr, int csw0, int csw1) {
    #pragma unroll
    for (int i = 0; i < 4; ++i) {
        const int rb = (mh * 64 + i * 16 + fr) * 128;
        a_[i][0] = *reinterpret_cast<const short8*>(slot + rb + csw0);
        a_[i][1] = *reinterpret_cast<const short8*>(slot + rb + csw1);
    }
}

__device__ __forceinline__ void load_b2(short8 b_[2][2], const char* slot, int rbase,
                                        int nh, int fr, int csw0, int csw1) {
    #pragma unroll
    for (int j = 0; j < 2; ++j) {
        const int rb = (rbase + nh * 32 + j * 16 + fr) * 128;
        b_[j][0] = *reinterpret_cast<const short8*>(slot + rb + csw0);
        b_[j][1] = *reinterpret_cast<const short8*>(slot + rb + csw1);
    }
}

__device__ __forceinline__ void mfma16(floatx4 acc[8][4], short8 a_[4][2],
                                       short8 b_[2][2], int mh, int nh) {
    __builtin_amdgcn_s_setprio(1);
    #pragma unroll
    for (int i = 0; i < 4; ++i)
        #pragma unroll
        for (int j = 0; j < 2; ++j) {
            acc[mh*4+i][nh*2+j] = __builtin_amdgcn_mfma_f32_16x16x32_bf16(
                a_[i][0], b_[j][0], acc[mh*4+i][nh*2+j], 0, 0, 0);
            acc[mh*4+i][nh*2+j] = __builtin_amdgcn_mfma_f32_16x16x32_bf16(
                a_[i][1], b_[j][1], acc[mh*4+i][nh*2+j], 0, 0, 0);
        }
    __builtin_amdgcn_s_setprio(0);
}

template<typename CT, int MODE>
__global__ __launch_bounds__(512, 2)
void gemm8p(const unsigned short* __restrict__ A, const unsigned short* B,
            const unsigned short* B1, CT* __restrict__ C, unsigned short* __restrict__ Vt,
            int K, int lda, int ldb, int ldc,
            long sA, long sB, long sC, int nwg)
{
    // XCD-aware bijective remap (T1, m204)
    const int gx = gridDim.x, gy = gridDim.y;
    int flat = (blockIdx.z * gy + blockIdx.y) * gx + blockIdx.x;
    {
        int xcd = flat & 7, lid = flat >> 3;
        int q = nwg >> 3, r = nwg & 7;
        flat = (xcd < r ? xcd * (q + 1) : r * (q + 1) + (xcd - r) * q) + lid;
    }
    int bx, by, bz = 0;
    bool isV = false;
    if (MODE == 1) {
        bx = flat % gx;
        int t2 = flat / gx;
        by = t2 % gy;
        bz = t2 / gy;
        if (bx > by) return;
    } else {            // MODE 3: dual job
        if (flat >= 128) { isV = true; flat -= 128; B = B1; }
        by = flat >> 2;  // m-tile 0..31
        bx = flat & 3;   // n-tile 0..3
    }

    A += (long)bz * sA + (long)by * 256 * lda;
    B += (long)bz * sB + (long)bx * 256 * ldb;
    C += (long)bz * sC;

    __shared__ __align__(16) char lds[8 * 16384];   // [db][op][half]
    #define SLOT(db, op, half) (lds + ((((db) << 1 | (op)) << 1 | (half)) * 16384))

    const int tid  = threadIdx.x;
    const int lane = tid & 63;
    const int wid  = tid >> 6;
    const int wm = wid >> 2;
    const int wn = wid & 3;
    const int bh = wn >> 1;
    const int brbase = (wn & 1) * 64;
    const int fr = lane & 15;
    const int csw0 = ((lane >> 4) * 16) ^ ((fr & 7) << 4);
    const int csw1 = (64 + (lane >> 4) * 16) ^ ((fr & 7) << 4);

    const unsigned short* Ah[2] = { A, A + 128ll * lda };
    const unsigned short* Bh[2] = { B, B + 128ll * ldb };

    const int NT = K >> 6;
    const int NI = NT >> 1;

    floatx4 acc[8][4] = {};
    short8 a_[4][2];
    short8 b_[2][2][2];

    stage_half(SLOT(0,1,0), Bh[0], ldb, 0, tid);
    stage_half(SLOT(0,1,1), Bh[1], ldb, 0, tid);
    stage_half(SLOT(0,0,0), Ah[0], lda, 0, tid);
    stage_half(SLOT(0,0,1), Ah[1], lda, 0, tid);
    stage_half(SLOT(1,1,0), Bh[0], ldb, 64, tid);
    stage_half(SLOT(1,1,1), Bh[1], ldb, 64, tid);
    WAITV4();
    BAR();

    for (int I = 0; I < NI; ++I) {
        const int kA1 = min(2*I + 1, NT - 1) * 64;
        const int kT2 = min(2*I + 2, NT - 1) * 64;
        const int kB3 = min(2*I + 3, NT - 1) * 64;

        load_a4(a_, SLOT(0,0,wm), 0, fr, csw0, csw1);
        load_b2(b_[0], SLOT(0,1,bh), brbase, 0, fr, csw0, csw1);
        stage_half(SLOT(1,0,0), Ah[0], lda, kA1, tid);
        BAR(); WAITL();
        mfma16(acc, a_, b_[0], 0, 0);
        BAR();

        load_b2(b_[1], SLOT(0,1,bh), brbase, 1, fr, csw0, csw1);
        stage_half(SLOT(1,0,1), Ah[1], lda, kA1, tid);
        BAR(); WAITL();
        mfma16(acc, a_, b_[1], 0, 1);
        BAR();

        load_a4(a_, SLOT(0,0,wm), 1, fr, csw0, csw1);
        stage_half(SLOT(0,1,0), Bh[0], ldb, kT2, tid);
        BAR(); WAITL();
        mfma16(acc, a_, b_[1], 1, 1);
        BAR();

        stage_half(SLOT(0,1,1), Bh[1], ldb, kT2, tid);
        BAR(); WAITL();
        mfma16(acc, a_, b_[0], 1, 0);
        WAITV4();
        BAR();

        load_a4(a_, SLOT(1,0,wm), 0, fr, csw0, csw1);
        load_b2(b_[0], SLOT(1,1,bh), brbase, 0, fr, csw0, csw1);
        stage_half(SLOT(0,0,0), Ah[0], lda, kT2, tid);
        BAR(); WAITL();
        mfma16(acc, a_, b_[0], 0, 0);
        BAR();

        load_b2(b_[1], SLOT(1,1,bh), brbase, 1, fr, csw0, csw1);
        stage_half(SLOT(0,0,1), Ah[1], lda, kT2, tid);
        BAR(); WAITL();
        mfma16(acc, a_, b_[1], 0, 1);
        BAR();

        load_a4(a_, SLOT(1,0,wm), 1, fr, csw0, csw1);
        stage_half(SLOT(1,1,0), Bh[0], ldb, kB3, tid);
        BAR(); WAITL();
        mfma16(acc, a_, b_[1], 1, 1);
        BAR();

        stage_half(SLOT(1,1,1), Bh[1], ldb, kB3, tid);
        BAR(); WAITL();
        mfma16(acc, a_, b_[0], 1, 0);
        WAITV4();
        BAR();
    }

    if (MODE == 3 && isV) {
        // V path: write C transposed into Vt[b][v][s] via LDS (coalesced)
        WAITV0();
        BAR();
        char* T = lds;   // 256(n) x 256(m) bf16, 16B-chunk XOR swizzle on m
        #pragma unroll
        for (int i = 0; i < 8; ++i)
            #pragma unroll
            for (int j = 0; j < 4; ++j) {
                const int n = wn * 64 + j * 16 + fr;
                const int m = wm * 128 + ((lane >> 4) << 2) + i * 16;
                uint2 pk;
                pk.x = (unsigned)f2bf(acc[i][j][0]) | ((unsigned)f2bf(acc[i][j][1]) << 16);
                pk.y = (unsigned)f2bf(acc[i][j][2]) | ((unsigned)f2bf(acc[i][j][3]) << 16);
                *reinterpret_cast<uint2*>(T + n * 512 + ((m * 2) ^ ((n & 7) << 4))) = pk;
            }
        __syncthreads();
        const int b  = by >> 3;
        const int s0 = (by & 7) * 256;
        #pragma unroll
        for (int c = 0; c < 16; ++c) {
            const int idx = c * 512 + tid;
            const int n = idx >> 5, k = idx & 31;
            uint4 v = *reinterpret_cast<const uint4*>(T + n * 512 + ((k * 16) ^ ((n & 7) << 4)));
            *reinterpret_cast<uint4*>(Vt + (long)b * (1024 * 2048)
                + (long)(bx * 256 + n) * 2048 + s0 + k * 8) = v;
        }
        return;
    }

    const int cr0 = by * 256 + wm * 128 + (lane >> 4) * 4;
    const int cc0 = bx * 256 + wn * 64 + (lane & 15);
    #pragma unroll
    for (int i = 0; i < 8; ++i)
        #pragma unroll
        for (int j = 0; j < 4; ++j)
            #pragma unroll
            for (int r = 0; r < 4; ++r) {
                long idx = (long)(cr0 + i * 16 + r) * ldc + (cc0 + j * 16);
                float v = acc[i][j][r];
                if constexpr (sizeof(CT) == 4) C[idx] = v;
                else                           C[idx] = (CT)f2bf(v);
            }
    #undef SLOT
}

// ===================== 128x128 2-phase GEMM =====================
// MODE 0: plain (G' one-off). MODE 2: causal K-limit (PV).
template<typename CT, int MODE>
__global__ __launch_bounds__(256, 3)
void gemm_bt(const unsigned short* __restrict__ A, const unsigned short* __restrict__ B,
             CT* __restrict__ C, int K, int lda, int ldb, int ldc,
             long sA, long sB, long sC, int nwg, float csc)
{
    const int gx = gridDim.x, gy = gridDim.y;
    int flat = (blockIdx.z * gy + blockIdx.y) * gx + blockIdx.x;
    {
        int xcd = flat & 7, lid = flat >> 3;
        int q = nwg >> 3, r = nwg & 7;
        flat = (xcd < r ? xcd * (q + 1) : r * (q + 1) + (xcd - r) * q) + lid;
    }
    int bx = flat % gx;
    int t2 = flat / gx;
    int by = t2 % gy;
    const int bz = t2 / gy;
    if (MODE == 2) {
        by = ((by & 1) << 3) | ((by & 2) << 1) | ((by & 4) >> 1) | ((by & 8) >> 3);
    }

    A += (long)bz * sA; B += (long)bz * sB; C += (long)bz * sC;
    const int kend = (MODE == 2) ? min(K, (by + 1) * 128) : K;

    __shared__ unsigned short As[128 * 64];
    __shared__ unsigned short Bs[128 * 64];

    const int tid  = threadIdx.x;
    const int lane = tid & 63;
    const int wid  = tid >> 6;
    const int m0 = by * 128, n0 = bx * 128;
    const int wm = (wid >> 1) * 64, wn = (wid & 1) * 64;
    const int frow = lane & 15;
    const int fk   = (lane >> 4) * 8;

    const int srow = lane >> 3;
    const int scolb = (lane & 7) * 16;

    floatx4 acc[4][4] = {};

    for (int k0 = 0; k0 < kend; k0 += 64) {
        __syncthreads();
        #pragma unroll
        for (int i = 0; i < 4; ++i) {
            const int c = wid * 4 + i;
            const int row = c * 8 + srow;
            const char* ga = reinterpret_cast<const char*>(A + (long)(m0 + row) * lda + k0) + scolb;
            __builtin_amdgcn_global_load_lds((gvp)ga,
                (lvp)(reinterpret_cast<char*>(As) + c * 1024), 16, 0, 0);
            const char* gb = reinterpret_cast<const char*>(B + (long)(n0 + row) * ldb + k0) + scolb;
            __builtin_amdgcn_global_load_lds((gvp)gb,
                (lvp)(reinterpret_cast<char*>(Bs) + c * 1024), 16, 0, 0);
        }
        __syncthreads();
        #pragma unroll
        for (int ks = 0; ks < 2; ++ks) {
            short8 af[4], bf[4];
            #pragma unroll
            for (int i = 0; i < 4; ++i) {
                const int ar = wm + i * 16 + frow;
                af[i] = *reinterpret_cast<const short8*>(
                    reinterpret_cast<const char*>(As) + ar * 128 + (ks * 32 + fk) * 2);
                const int br = wn + i * 16 + frow;
                bf[i] = *reinterpret_cast<const short8*>(
                    reinterpret_cast<const char*>(Bs) + br * 128 + (ks * 32 + fk) * 2);
            }
            #pragma unroll
            for (int i = 0; i < 4; ++i)
                #pragma unroll
                for (int j = 0; j < 4; ++j)
                    acc[i][j] = __builtin_amdgcn_mfma_f32_16x16x32_bf16(af[i], bf[j], acc[i][j], 0, 0, 0);
        }
    }

    const int cr0 = m0 + wm + (lane >> 4) * 4;
    const int cc0 = n0 + wn + (lane & 15);
    #pragma unroll
    for (int i = 0; i < 4; ++i)
        #pragma unroll
        for (int j = 0; j < 4; ++j)
            #pragma unroll
            for (int r = 0; r < 4; ++r) {
                long idx = (long)(cr0 + i * 16 + r) * ldc + (cc0 + j * 16);
                float v = acc[i][j][r] * csc;
                if constexpr (sizeof(CT) == 4) C[idx] = v;
                else                           C[idx] = (CT)f2bf(v);
            }
}

// ---------------- causal softmax (scores pre-scaled via G); bf16 probs in place ----------------
__global__ __launch_bounds__(256)
void softmax_causal(float* __restrict__ Sc) {
    const int q = blockIdx.x;
    const int b = blockIdx.y;
    float* row = Sc + ((long)b * 2048 + q) * 2048;
    const int t = threadIdx.x;
    const int lane = t & 63, wid = t >> 6;
    const int kend = (q | 127) + 1;       // PV reads exactly cols < kend

    float vals[8];
    float mx = -INFINITY;
    #pragma unroll
    for (int i = 0; i < 2; ++i) {
        const int c0 = i * 1024 + t * 4;
        if (c0 <= q) {
            float4 v = *reinterpret_cast<const float4*>(row + c0);
            float tmp[4] = {v.x, v.y, v.z, v.w};
            #pragma unroll
            for (int j = 0; j < 4; ++j) {
                float val = (c0 + j <= q) ? tmp[j] : -INFINITY;
                vals[i * 4 + j] = val;
                mx = fmaxf(mx, val);
            }
        } else {
            vals[i*4+0] = vals[i*4+1] = vals[i*4+2] = vals[i*4+3] = -INFINITY;
        }
    }
    #pragma unroll
    for (int o = 32; o > 0; o >>= 1) mx = fmaxf(mx, __shfl_xor(mx, o));
    __shared__ float rmax[4], rsum[4];
    if (lane == 0) rmax[wid] = mx;
    __syncthreads();
    mx = fmaxf(fmaxf(rmax[0], rmax[1]), fmaxf(rmax[2], rmax[3]));

    float s = 0.f;
    #pragma unroll
    for (int k = 0; k < 8; ++k) {
        float e = __expf(vals[k] - mx);
        vals[k] = e;
        s += e;
    }
    #pragma unroll
    for (int o = 32; o > 0; o >>= 1) s += __shfl_xor(s, o);
    if (lane == 0) rsum[wid] = s;
    __syncthreads();
    s = rsum[0] + rsum[1] + rsum[2] + rsum[3];
    const float inv = 1.f / s;

    unsigned short* orow = reinterpret_cast<unsigned short*>(row);
    #pragma unroll
    for (int i = 0; i < 2; ++i) {
        const int c0 = i * 1024 + t * 4;
        if (c0 < kend) {
            uint2 o;
            o.x = (unsigned)f2bf(vals[i*4+0] * inv) | ((unsigned)f2bf(vals[i*4+1] * inv) << 16);
            o.y = (unsigned)f2bf(vals[i*4+2] * inv) | ((unsigned)f2bf(vals[i*4+3] * inv) << 16);
            *reinterpret_cast<uint2*>(orow + c0) = o;
        }
    }
}

extern "C" void kernel_launch(void* const* d_in, const int* in_sizes, int n_in,
                              void* d_out, int out_size, void* d_ws, size_t ws_size,
                              hipStream_t stream) {
    const float* x  = (const float*)d_in[0];
    const float* Wq = (const float*)d_in[1];
    const float* Wk = (const float*)d_in[2];
    const float* Wv = (const float*)d_in[3];
    float* out = (float*)d_out;

    // ws layout: Xb@0 (16M) | WqT@16M (2M) | WkT@18M (2M) | Wvb@20M (2M) |
    //            Y@22M (16M) | G@38M (2M) | Vt@70M (16M) | Sc@86M (64M)
    char* w = (char*)d_ws;
    unsigned short* Xb  = (unsigned short*)(w);
    unsigned short* WqT = (unsigned short*)(w + (16ll << 20));
    unsigned short* WkT = (unsigned short*)(w + (18ll << 20));
    unsigned short* Wvb = (unsigned short*)(w + (20ll << 20));
    unsigned short* Yb  = (unsigned short*)(w + (22ll << 20));
    unsigned short* Gp  = (unsigned short*)(w + (38ll << 20));
    unsigned short* Vt  = (unsigned short*)(w + (70ll << 20));
    float* Sc = (float*)(w + (86ll << 20));

    dim3 blk(256);
    cvt_all<<<2816, blk, 0, stream>>>(x, Wq, Wk, Wv, Xb, WqT, WkT, Wvb);

    // G = (Wk^T Wq) * 1/sqrt(1024)  [1024x1024 bf16]: G[m,n] = sum_e Wk[e,m] Wq[e,n]
    gemm_bt<unsigned short, 0><<<dim3(8, 8, 1), blk, 0, stream>>>(
        WkT, WqT, Gp, 1024, 1024, 1024, 1024, 0, 0, 0, 64, 0.03125f);

    // Y = X*G (scores-left factor) AND V-proj (transposed write) in ONE 256-block dispatch
    gemm8p<unsigned short, 3><<<dim3(256, 1, 1), dim3(512), 0, stream>>>(
        Xb, Gp, Wvb, Yb, Vt, 1024, 1024, 1024, 1024,
        0, 0, 0, 256);

    // scores = Y @ X^T (pre-scaled), causal tile skip
    gemm8p<float, 1><<<dim3(8, 8, 4), dim3(512), 0, stream>>>(
        Yb, Xb, nullptr, Sc, nullptr, 1024, 1024, 1024, 2048,
        2048ll * 1024, 2048ll * 1024, 2048ll * 2048, 256);

    softmax_causal<<<dim3(2048, 4), blk, 0, stream>>>(Sc);

    // out = P @ V   (128^2 2-phase, K-causal)
    gemm_bt<float, 2><<<dim3(8, 16, 4), blk, 0, stream>>>(
        (const unsigned short*)Sc, Vt, out, 2048, 4096, 2048, 1024,
        2048ll * 4096, 1024ll * 2048, 2048ll * 1024, 512, 1.0f);
}

// Round 6
// 145.311 us; speedup vs baseline: 1.3221x; 1.1111x over previous
//
#include <hip/hip_runtime.h>
#include <hip/hip_bf16.h>
#include <stdint.h>

typedef __attribute__((ext_vector_type(8))) short short8;
typedef __attribute__((ext_vector_type(4))) float floatx4;

typedef const __attribute__((address_space(1))) void* gvp;
typedef __attribute__((address_space(3))) void* lvp;

__device__ __forceinline__ unsigned short f2bf(float f) {
    unsigned u = __float_as_uint(f);
    u += 0x7fffu + ((u >> 16) & 1u);   // RNE
    return (unsigned short)(u >> 16);
}

#define BAR()   do { asm volatile("" ::: "memory"); __builtin_amdgcn_s_barrier(); asm volatile("" ::: "memory"); } while (0)
#define WAITL() do { asm volatile("s_waitcnt lgkmcnt(0)" ::: "memory"); __builtin_amdgcn_sched_barrier(0); } while (0)
#define WAITV4() asm volatile("s_waitcnt vmcnt(4)" ::: "memory")
#define WAITV0() asm volatile("s_waitcnt vmcnt(0)" ::: "memory")

// ---------------- conversion: X, Wv straight; Wq, Wk transposed (for G) ----------------
__global__ __launch_bounds__(256)
void cvt_all(const float* __restrict__ x, const float* __restrict__ wq,
             const float* __restrict__ wk, const float* __restrict__ wv,
             unsigned short* __restrict__ Xb, unsigned short* __restrict__ WqT,
             unsigned short* __restrict__ WkT, unsigned short* __restrict__ Wvb) {
    const int b = blockIdx.x, t = threadIdx.x;
    if (b < 2304) {
        const float* in; unsigned short* out; long base;
        if (b < 2048) { in = x;  out = Xb;  base = (long)b * 1024; }
        else          { in = wv; out = Wvb; base = (long)(b - 2048) * 1024; }
        #pragma unroll
        for (int k = 0; k < 4; ++k) {
            long idx = base + k * 256 + t;
            float4 v = reinterpret_cast<const float4*>(in)[idx];
            uint2 o;
            o.x = (unsigned)f2bf(v.x) | ((unsigned)f2bf(v.y) << 16);
            o.y = (unsigned)f2bf(v.z) | ((unsigned)f2bf(v.w) << 16);
            reinterpret_cast<uint2*>(out)[idx] = o;
        }
    } else {
        const int bb = b - 2304;
        const float* in = (bb < 256) ? wq : wk;
        unsigned short* out = (bb < 256) ? WqT : WkT;
        const int tile = bb & 255;
        const int e0 = (tile >> 4) * 64, d0 = (tile & 15) * 64;
        __shared__ unsigned short ldsT[64][68];
        const int r = t >> 4, cq = t & 15;
        #pragma unroll
        for (int p = 0; p < 4; ++p) {
            const int e = p * 16 + r;
            float4 v = *reinterpret_cast<const float4*>(in + (long)(e0 + e) * 1024 + d0 + cq * 4);
            ldsT[cq*4+0][e] = f2bf(v.x);
            ldsT[cq*4+1][e] = f2bf(v.y);
            ldsT[cq*4+2][e] = f2bf(v.z);
            ldsT[cq*4+3][e] = f2bf(v.w);
        }
        __syncthreads();
        #pragma unroll
        for (int p = 0; p < 4; ++p) {
            const int d = p * 16 + r;
            ushort4 o = *reinterpret_cast<const ushort4*>(&ldsT[d][cq * 4]);
            *reinterpret_cast<ushort4*>(out + (long)(d0 + d) * 1024 + e0 + cq * 4) = o;
        }
    }
}

// ===================== 128x128 dbuf engine (T2 swizzle + depth-2 prefetch) =====================
__device__ __forceinline__ void stage_tile(unsigned short* Abuf, unsigned short* Bbuf,
                                           const unsigned short* A, int lda,
                                           const unsigned short* B, int ldb, int k0,
                                           int wid, int srow, int piece) {
    #pragma unroll
    for (int i = 0; i < 4; ++i) {
        const int c = wid * 4 + i;
        const int row = c * 8 + srow;
        const int cs = (piece * 16) ^ ((row & 7) << 4);   // pre-swizzled source col
        __builtin_amdgcn_global_load_lds(
            (gvp)(reinterpret_cast<const char*>(A + (long)row * lda + k0) + cs),
            (lvp)(reinterpret_cast<char*>(Abuf) + c * 1024), 16, 0, 0);
        __builtin_amdgcn_global_load_lds(
            (gvp)(reinterpret_cast<const char*>(B + (long)row * ldb + k0) + cs),
            (lvp)(reinterpret_cast<char*>(Bbuf) + c * 1024), 16, 0, 0);
    }
}

__device__ __forceinline__ void compute_tile(floatx4 acc[4][4], const unsigned short* As,
                                             const unsigned short* Bs, int wm, int wn,
                                             int frow, int lane) {
    #pragma unroll
    for (int ks = 0; ks < 2; ++ks) {
        short8 af[4], bf[4];
        const int colb = ks * 64 + (lane >> 4) * 16;
        #pragma unroll
        for (int i = 0; i < 4; ++i) {
            const int ar = wm + i * 16 + frow;
            af[i] = *reinterpret_cast<const short8*>(
                reinterpret_cast<const char*>(As) + ar * 128 + (colb ^ ((ar & 7) << 4)));
            const int br = wn + i * 16 + frow;
            bf[i] = *reinterpret_cast<const short8*>(
                reinterpret_cast<const char*>(Bs) + br * 128 + (colb ^ ((br & 7) << 4)));
        }
        #pragma unroll
        for (int i = 0; i < 4; ++i)
            #pragma unroll
            for (int j = 0; j < 4; ++j)
                acc[i][j] = __builtin_amdgcn_mfma_f32_16x16x32_bf16(af[i], bf[j], acc[i][j], 0, 0, 0);
    }
}

// ---- G split-K chunk: Gw[bz] += WkT-tile x WqT-tile over k in [bz*256, bz*256+256) ----
__global__ __launch_bounds__(256, 2)
void g_chunk(const unsigned short* __restrict__ WkT, const unsigned short* __restrict__ WqT,
             float* __restrict__ Gw) {
    const int bx = blockIdx.x, by = blockIdx.y, bz = blockIdx.z;
    const unsigned short* A = WkT + (long)by * 128 * 1024;
    const unsigned short* B = WqT + (long)bx * 128 * 1024;

    __shared__ unsigned short As[2][128 * 64];
    __shared__ unsigned short Bs[2][128 * 64];

    const int tid = threadIdx.x, lane = tid & 63, wid = tid >> 6;
    const int srow = lane >> 3, piece = lane & 7;
    const int wm = (wid >> 1) * 64, wn = (wid & 1) * 64, frow = lane & 15;

    floatx4 acc[4][4] = {};
    const int kbase = bz * 256;

    stage_tile(As[0], Bs[0], A, 1024, B, 1024, kbase, wid, srow, piece);
    WAITV0(); BAR();
    int cur = 0;
    #pragma unroll 1
    for (int t = 0; t < 4; ++t) {
        if (t < 3)
            stage_tile(As[cur ^ 1], Bs[cur ^ 1], A, 1024, B, 1024, kbase + (t + 1) * 64,
                       wid, srow, piece);
        compute_tile(acc, As[cur], Bs[cur], wm, wn, frow, lane);
        WAITV0(); BAR();
        cur ^= 1;
    }

    float* Cb = Gw + (long)bz * (1 << 20) + (long)(by * 128) * 1024 + bx * 128;
    const int cr0 = wm + (lane >> 4) * 4;
    const int cc0 = wn + (lane & 15);
    #pragma unroll
    for (int i = 0; i < 4; ++i)
        #pragma unroll
        for (int j = 0; j < 4; ++j)
            #pragma unroll
            for (int r = 0; r < 4; ++r)
                Cb[(long)(cr0 + i * 16 + r) * 1024 + cc0 + j * 16] = acc[i][j][r];
}

// ---- reduce 4 G chunks -> bf16 G (scaled by 1/sqrt(1024)) ----
__global__ __launch_bounds__(256)
void reduce_g(const float* __restrict__ Gw, unsigned short* __restrict__ Gp) {
    const long i4 = (long)blockIdx.x * 256 + threadIdx.x;   // float4 index, 2^18 total
    const long M4 = (1l << 20) / 4;
    float4 a = reinterpret_cast<const float4*>(Gw)[i4];
    float4 b = reinterpret_cast<const float4*>(Gw)[i4 + M4];
    float4 c = reinterpret_cast<const float4*>(Gw)[i4 + 2 * M4];
    float4 d = reinterpret_cast<const float4*>(Gw)[i4 + 3 * M4];
    float sx = (a.x + b.x + c.x + d.x) * 0.03125f;
    float sy = (a.y + b.y + c.y + d.y) * 0.03125f;
    float sz = (a.z + b.z + c.z + d.z) * 0.03125f;
    float sw = (a.w + b.w + c.w + d.w) * 0.03125f;
    uint2 o;
    o.x = (unsigned)f2bf(sx) | ((unsigned)f2bf(sy) << 16);
    o.y = (unsigned)f2bf(sz) | ((unsigned)f2bf(sw) << 16);
    reinterpret_cast<uint2*>(Gp)[i4] = o;
}

// ---- PV with complementary pairing: block does tiles (pj, 15-pj) -> uniform 17 K-steps ----
__global__ __launch_bounds__(256, 2)
void pv_pair(const unsigned short* __restrict__ P, const unsigned short* __restrict__ Vt,
             float* __restrict__ out) {
    // XCD-aware bijective remap (T1): 256 blocks
    int flat = (blockIdx.z * 8 + blockIdx.y) * 8 + blockIdx.x;
    { int xcd = flat & 7, lid = flat >> 3; flat = xcd * 32 + lid; }
    const int bx = flat % 8;
    const int pj = (flat / 8) % 8;
    const int bz = flat / 64;

    const unsigned short* Pb = P + (long)bz * 2048 * 4096;   // bf16 view of f32 rows
    const unsigned short* Bv = Vt + (long)bz * 1024 * 2048 + (long)(bx * 128) * 2048;
    float* Cb = out + (long)bz * 2048 * 1024;

    __shared__ unsigned short As[2][128 * 64];
    __shared__ unsigned short Bs[2][128 * 64];

    const int tid = threadIdx.x, lane = tid & 63, wid = tid >> 6;
    const int srow = lane >> 3, piece = lane & 7;
    const int wm = (wid >> 1) * 64, wn = (wid & 1) * 64, frow = lane & 15;

    #pragma unroll 1
    for (int j = 0; j < 2; ++j) {
        const int by = j ? 15 - pj : pj;
        const unsigned short* A = Pb + (long)by * 128 * 4096;
        const int nt = (by + 1) * 2;   // K-tiles of 64

        floatx4 acc[4][4] = {};
        stage_tile(As[0], Bs[0], A, 4096, Bv, 2048, 0, wid, srow, piece);
        WAITV0(); BAR();
        int cur = 0;
        #pragma unroll 1
        for (int t = 0; t < nt; ++t) {
            if (t + 1 < nt)
                stage_tile(As[cur ^ 1], Bs[cur ^ 1], A, 4096, Bv, 2048, (t + 1) * 64,
                           wid, srow, piece);
            compute_tile(acc, As[cur], Bs[cur], wm, wn, frow, lane);
            WAITV0(); BAR();
            cur ^= 1;
        }

        float* Cj = Cb + (long)(by * 128) * 1024 + bx * 128;
        const int cr0 = wm + (lane >> 4) * 4;
        const int cc0 = wn + (lane & 15);
        #pragma unroll
        for (int i = 0; i < 4; ++i)
            #pragma unroll
            for (int jj = 0; jj < 4; ++jj)
                #pragma unroll
                for (int r = 0; r < 4; ++r)
                    Cj[(long)(cr0 + i * 16 + r) * 1024 + cc0 + jj * 16] = acc[i][jj][r];
    }
}

// ===================== 256x256 8-phase GEMM (unchanged engine) =====================
__device__ __forceinline__ void stage_half(char* slot, const unsigned short* src,
                                           int ld, int k0, int tid) {
    #pragma unroll
    for (int r = 0; r < 2; ++r) {
        const int c = r * 512 + tid;
        const int row = c >> 3;
        const int cs = ((c & 7) * 16) ^ ((row & 7) << 4);
        const char* g = reinterpret_cast<const char*>(src + (long)row * ld + k0) + cs;
        __builtin_amdgcn_global_load_lds((gvp)g,
            (lvp)(slot + r * 8192 + (tid >> 6) * 1024), 16, 0, 0);
    }
}

__device__ __forceinline__ void load_a4(short8 a_[4][2], const char* slot, int mh,
                                        int fr, int csw0, int csw1) {
    #pragma unroll
    for (int i = 0; i < 4; ++i) {
        const int rb = (mh * 64 + i * 16 + fr) * 128;
        a_[i][0] = *reinterpret_cast<const short8*>(slot + rb + csw0);
        a_[i][1] = *reinterpret_cast<const short8*>(slot + rb + csw1);
    }
}

__device__ __forceinline__ void load_b2(short8 b_[2][2], const char* slot, int rbase,
                                        int nh, int fr, int csw0, int csw1) {
    #pragma unroll
    for (int j = 0; j < 2; ++j) {
        const int rb = (rbase + nh * 32 + j * 16 + fr) * 128;
        b_[j][0] = *reinterpret_cast<const short8*>(slot + rb + csw0);
        b_[j][1] = *reinterpret_cast<const short8*>(slot + rb + csw1);
    }
}

__device__ __forceinline__ void mfma16(floatx4 acc[8][4], short8 a_[4][2],
                                       short8 b_[2][2], int mh, int nh) {
    __builtin_amdgcn_s_setprio(1);
    #pragma unroll
    for (int i = 0; i < 4; ++i)
        #pragma unroll
        for (int j = 0; j < 2; ++j) {
            acc[mh*4+i][nh*2+j] = __builtin_amdgcn_mfma_f32_16x16x32_bf16(
                a_[i][0], b_[j][0], acc[mh*4+i][nh*2+j], 0, 0, 0);
            acc[mh*4+i][nh*2+j] = __builtin_amdgcn_mfma_f32_16x16x32_bf16(
                a_[i][1], b_[j][1], acc[mh*4+i][nh*2+j], 0, 0, 0);
        }
    __builtin_amdgcn_s_setprio(0);
}

template<typename CT, int MODE>
__global__ __launch_bounds__(512, 2)
void gemm8p(const unsigned short* __restrict__ A, const unsigned short* B,
            const unsigned short* B1, CT* __restrict__ C, unsigned short* __restrict__ Vt,
            int K, int lda, int ldb, int ldc,
            long sA, long sB, long sC, int nwg)
{
    const int gx = gridDim.x, gy = gridDim.y;
    int flat = (blockIdx.z * gy + blockIdx.y) * gx + blockIdx.x;
    {
        int xcd = flat & 7, lid = flat >> 3;
        int q = nwg >> 3, r = nwg & 7;
        flat = (xcd < r ? xcd * (q + 1) : r * (q + 1) + (xcd - r) * q) + lid;
    }
    int bx, by, bz = 0;
    bool isV = false;
    if (MODE == 1) {
        bx = flat % gx;
        int t2 = flat / gx;
        by = t2 % gy;
        bz = t2 / gy;
        if (bx > by) return;
    } else {            // MODE 3: dual job
        if (flat >= 128) { isV = true; flat -= 128; B = B1; }
        by = flat >> 2;
        bx = flat & 3;
    }

    A += (long)bz * sA + (long)by * 256 * lda;
    B += (long)bz * sB + (long)bx * 256 * ldb;
    C += (long)bz * sC;

    __shared__ __align__(16) char lds[8 * 16384];
    #define SLOT(db, op, half) (lds + ((((db) << 1 | (op)) << 1 | (half)) * 16384))

    const int tid  = threadIdx.x;
    const int lane = tid & 63;
    const int wid  = tid >> 6;
    const int wm = wid >> 2;
    const int wn = wid & 3;
    const int bh = wn >> 1;
    const int brbase = (wn & 1) * 64;
    const int fr = lane & 15;
    const int csw0 = ((lane >> 4) * 16) ^ ((fr & 7) << 4);
    const int csw1 = (64 + (lane >> 4) * 16) ^ ((fr & 7) << 4);

    const unsigned short* Ah[2] = { A, A + 128ll * lda };
    const unsigned short* Bh[2] = { B, B + 128ll * ldb };

    const int NT = K >> 6;
    const int NI = NT >> 1;

    floatx4 acc[8][4] = {};
    short8 a_[4][2];
    short8 b_[2][2][2];

    stage_half(SLOT(0,1,0), Bh[0], ldb, 0, tid);
    stage_half(SLOT(0,1,1), Bh[1], ldb, 0, tid);
    stage_half(SLOT(0,0,0), Ah[0], lda, 0, tid);
    stage_half(SLOT(0,0,1), Ah[1], lda, 0, tid);
    stage_half(SLOT(1,1,0), Bh[0], ldb, 64, tid);
    stage_half(SLOT(1,1,1), Bh[1], ldb, 64, tid);
    WAITV4();
    BAR();

    for (int I = 0; I < NI; ++I) {
        const int kA1 = min(2*I + 1, NT - 1) * 64;
        const int kT2 = min(2*I + 2, NT - 1) * 64;
        const int kB3 = min(2*I + 3, NT - 1) * 64;

        load_a4(a_, SLOT(0,0,wm), 0, fr, csw0, csw1);
        load_b2(b_[0], SLOT(0,1,bh), brbase, 0, fr, csw0, csw1);
        stage_half(SLOT(1,0,0), Ah[0], lda, kA1, tid);
        BAR(); WAITL();
        mfma16(acc, a_, b_[0], 0, 0);
        BAR();

        load_b2(b_[1], SLOT(0,1,bh), brbase, 1, fr, csw0, csw1);
        stage_half(SLOT(1,0,1), Ah[1], lda, kA1, tid);
        BAR(); WAITL();
        mfma16(acc, a_, b_[1], 0, 1);
        BAR();

        load_a4(a_, SLOT(0,0,wm), 1, fr, csw0, csw1);
        stage_half(SLOT(0,1,0), Bh[0], ldb, kT2, tid);
        BAR(); WAITL();
        mfma16(acc, a_, b_[1], 1, 1);
        BAR();

        stage_half(SLOT(0,1,1), Bh[1], ldb, kT2, tid);
        BAR(); WAITL();
        mfma16(acc, a_, b_[0], 1, 0);
        WAITV4();
        BAR();

        load_a4(a_, SLOT(1,0,wm), 0, fr, csw0, csw1);
        load_b2(b_[0], SLOT(1,1,bh), brbase, 0, fr, csw0, csw1);
        stage_half(SLOT(0,0,0), Ah[0], lda, kT2, tid);
        BAR(); WAITL();
        mfma16(acc, a_, b_[0], 0, 0);
        BAR();

        load_b2(b_[1], SLOT(1,1,bh), brbase, 1, fr, csw0, csw1);
        stage_half(SLOT(0,0,1), Ah[1], lda, kT2, tid);
        BAR(); WAITL();
        mfma16(acc, a_, b_[1], 0, 1);
        BAR();

        load_a4(a_, SLOT(1,0,wm), 1, fr, csw0, csw1);
        stage_half(SLOT(1,1,0), Bh[0], ldb, kB3, tid);
        BAR(); WAITL();
        mfma16(acc, a_, b_[1], 1, 1);
        BAR();

        stage_half(SLOT(1,1,1), Bh[1], ldb, kB3, tid);
        BAR(); WAITL();
        mfma16(acc, a_, b_[0], 1, 0);
        WAITV4();
        BAR();
    }

    if (MODE == 3 && isV) {
        WAITV0();
        BAR();
        char* T = lds;
        #pragma unroll
        for (int i = 0; i < 8; ++i)
            #pragma unroll
            for (int j = 0; j < 4; ++j) {
                const int n = wn * 64 + j * 16 + fr;
                const int m = wm * 128 + ((lane >> 4) << 2) + i * 16;
                uint2 pk;
                pk.x = (unsigned)f2bf(acc[i][j][0]) | ((unsigned)f2bf(acc[i][j][1]) << 16);
                pk.y = (unsigned)f2bf(acc[i][j][2]) | ((unsigned)f2bf(acc[i][j][3]) << 16);
                *reinterpret_cast<uint2*>(T + n * 512 + ((m * 2) ^ ((n & 7) << 4))) = pk;
            }
        __syncthreads();
        const int b  = by >> 3;
        const int s0 = (by & 7) * 256;
        #pragma unroll
        for (int c = 0; c < 16; ++c) {
            const int idx = c * 512 + tid;
            const int n = idx >> 5, k = idx & 31;
            uint4 v = *reinterpret_cast<const uint4*>(T + n * 512 + ((k * 16) ^ ((n & 7) << 4)));
            *reinterpret_cast<uint4*>(Vt + (long)b * (1024 * 2048)
                + (long)(bx * 256 + n) * 2048 + s0 + k * 8) = v;
        }
        return;
    }

    const int cr0 = by * 256 + wm * 128 + (lane >> 4) * 4;
    const int cc0 = bx * 256 + wn * 64 + (lane & 15);
    #pragma unroll
    for (int i = 0; i < 8; ++i)
        #pragma unroll
        for (int j = 0; j < 4; ++j)
            #pragma unroll
            for (int r = 0; r < 4; ++r) {
                long idx = (long)(cr0 + i * 16 + r) * ldc + (cc0 + j * 16);
                float v = acc[i][j][r];
                if constexpr (sizeof(CT) == 4) C[idx] = v;
                else                           C[idx] = (CT)f2bf(v);
            }
    #undef SLOT
}

// ---------------- causal softmax (scores pre-scaled via G); bf16 probs in place ----------------
__global__ __launch_bounds__(256)
void softmax_causal(float* __restrict__ Sc) {
    const int q = blockIdx.x;
    const int b = blockIdx.y;
    float* row = Sc + ((long)b * 2048 + q) * 2048;
    const int t = threadIdx.x;
    const int lane = t & 63, wid = t >> 6;
    const int kend = (q | 127) + 1;

    float vals[8];
    float mx = -INFINITY;
    #pragma unroll
    for (int i = 0; i < 2; ++i) {
        const int c0 = i * 1024 + t * 4;
        if (c0 <= q) {
            float4 v = *reinterpret_cast<const float4*>(row + c0);
            float tmp[4] = {v.x, v.y, v.z, v.w};
            #pragma unroll
            for (int j = 0; j < 4; ++j) {
                float val = (c0 + j <= q) ? tmp[j] : -INFINITY;
                vals[i * 4 + j] = val;
                mx = fmaxf(mx, val);
            }
        } else {
            vals[i*4+0] = vals[i*4+1] = vals[i*4+2] = vals[i*4+3] = -INFINITY;
        }
    }
    #pragma unroll
    for (int o = 32; o > 0; o >>= 1) mx = fmaxf(mx, __shfl_xor(mx, o));
    __shared__ float rmax[4], rsum[4];
    if (lane == 0) rmax[wid] = mx;
    __syncthreads();
    mx = fmaxf(fmaxf(rmax[0], rmax[1]), fmaxf(rmax[2], rmax[3]));

    float s = 0.f;
    #pragma unroll
    for (int k = 0; k < 8; ++k) {
        float e = __expf(vals[k] - mx);
        vals[k] = e;
        s += e;
    }
    #pragma unroll
    for (int o = 32; o > 0; o >>= 1) s += __shfl_xor(s, o);
    if (lane == 0) rsum[wid] = s;
    __syncthreads();
    s = rsum[0] + rsum[1] + rsum[2] + rsum[3];
    const float inv = 1.f / s;

    unsigned short* orow = reinterpret_cast<unsigned short*>(row);
    #pragma unroll
    for (int i = 0; i < 2; ++i) {
        const int c0 = i * 1024 + t * 4;
        if (c0 < kend) {
            uint2 o;
            o.x = (unsigned)f2bf(vals[i*4+0] * inv) | ((unsigned)f2bf(vals[i*4+1] * inv) << 16);
            o.y = (unsigned)f2bf(vals[i*4+2] * inv) | ((unsigned)f2bf(vals[i*4+3] * inv) << 16);
            *reinterpret_cast<uint2*>(orow + c0) = o;
        }
    }
}

extern "C" void kernel_launch(void* const* d_in, const int* in_sizes, int n_in,
                              void* d_out, int out_size, void* d_ws, size_t ws_size,
                              hipStream_t stream) {
    const float* x  = (const float*)d_in[0];
    const float* Wq = (const float*)d_in[1];
    const float* Wk = (const float*)d_in[2];
    const float* Wv = (const float*)d_in[3];
    float* out = (float*)d_out;

    // ws: Xb@0(16M) WqT@16M(2M) WkT@18M(2M) Wvb@20M(2M) Yb@22M(16M) G@38M(2M)
    //     Gw@40M(16M f32 partials) Vt@70M(16M) Sc@86M(64M)
    char* w = (char*)d_ws;
    unsigned short* Xb  = (unsigned short*)(w);
    unsigned short* WqT = (unsigned short*)(w + (16ll << 20));
    unsigned short* WkT = (unsigned short*)(w + (18ll << 20));
    unsigned short* Wvb = (unsigned short*)(w + (20ll << 20));
    unsigned short* Yb  = (unsigned short*)(w + (22ll << 20));
    unsigned short* Gp  = (unsigned short*)(w + (38ll << 20));
    float*          Gw  = (float*)(w + (40ll << 20));
    unsigned short* Vt  = (unsigned short*)(w + (70ll << 20));
    float* Sc = (float*)(w + (86ll << 20));

    dim3 blk(256);
    cvt_all<<<2816, blk, 0, stream>>>(x, Wq, Wk, Wv, Xb, WqT, WkT, Wvb);

    // G^T = (Wk^T Wq) split-K over 4 chunks, then reduce+scale to bf16
    g_chunk<<<dim3(8, 8, 4), blk, 0, stream>>>(WkT, WqT, Gw);
    reduce_g<<<1024, blk, 0, stream>>>(Gw, Gp);

    // Y = X*G AND V-proj (transposed write) in ONE 256-block 8-phase dispatch
    gemm8p<unsigned short, 3><<<dim3(256, 1, 1), dim3(512), 0, stream>>>(
        Xb, Gp, Wvb, Yb, Vt, 1024, 1024, 1024, 1024,
        0, 0, 0, 256);

    // scores = Y @ X^T (pre-scaled), causal tile skip
    gemm8p<float, 1><<<dim3(8, 8, 4), dim3(512), 0, stream>>>(
        Yb, Xb, nullptr, Sc, nullptr, 1024, 1024, 1024, 2048,
        2048ll * 1024, 2048ll * 1024, 2048ll * 2048, 256);

    softmax_causal<<<dim3(2048, 4), blk, 0, stream>>>(Sc);

    // out = P @ V  (complementary-paired 128^2 dbuf blocks, uniform 17 K-steps)
    pv_pair<<<dim3(8, 8, 4), blk, 0, stream>>>((const unsigned short*)Sc, Vt, out);
}